// Round 9
// baseline (460.388 us; speedup 1.0000x reference)
//
#include <hip/hip_runtime.h>
#include <hip/hip_bf16.h>
#include <hip/hip_cooperative_groups.h>
#include <math.h>

namespace cg = cooperative_groups;

// Problem dims (fixed by setup_inputs)
#define B_  8
#define CM  80
#define T1_ 800
#define CT  512
#define T2_ 200
#define CA  80

using bf16 = __hip_bfloat16;
typedef __attribute__((ext_vector_type(8))) short bf16x8;
typedef __attribute__((ext_vector_type(4))) float f32x4;

#define LDSW 56
#define NBLK 512

__device__ __forceinline__ float load_sel(const void* p, long idx, int isf32) {
  if (isf32) return ((const float*)p)[idx];
  return __bfloat162float(((const bf16*)p)[idx]);
}

__device__ __forceinline__ unsigned short f2bf(float x) {
  bf16 h = __float2bfloat16(x);
  return *reinterpret_cast<unsigned short*>(&h);
}

// Inline dtype probe (R8-proven): fp32-stored data puts mantissa bits in the
// even uint16 halves -> insane bf16 exponents.
__device__ __forceinline__ int detect_f32(const unsigned short* q) {
  __shared__ int s_f;
  const int tid = threadIdx.x;
  if (tid < 64) {
    unsigned short u = q[2 * tid];
    int e = (u >> 7) & 0xFF;
    unsigned long long bal = __ballot(e < 100 || e > 154);
    if (tid == 0) s_f = (__popcll(bal) >= 16) ? 1 : 0;
  }
  __syncthreads();
  return s_f;
}

// --- prep tasks (R8-proven bodies, smem passed in) ---
__device__ void task_cvt_t(const void* X, bf16* XT, int f, int C, int T,
                           int id2, int tilesT, float* smem, int tid) {
  __syncthreads();  // protect smem reuse across jobs
  const int per_b = tilesT * ((C + 31) >> 5);
  const int b = id2 / per_b;
  const int r = id2 - b * per_b;
  const int ct = r / tilesT, tt = r - ct * tilesT;
  const int c0 = ct * 32, t0 = tt * 32;
  const int tx = tid & 31, trow = tid >> 5;
#pragma unroll
  for (int p = 0; p < 4; ++p) {
    const int cr = trow + 8 * p;
    if (c0 + cr < C && t0 + tx < T)
      smem[cr * 33 + tx] = load_sel(X, ((long)b * C + c0 + cr) * T + t0 + tx, f);
  }
  __syncthreads();
#pragma unroll
  for (int p = 0; p < 4; ++p) {
    const int tr = trow + 8 * p;
    if (t0 + tr < T && c0 + tx < C)
      XT[((long)b * T + t0 + tr) * C + c0 + tx] =
          __float2bfloat16(smem[tx * 33 + tr]);
  }
}

__device__ void task_wt3(const void* W, bf16* WT, int f, int Co, int Ci,
                         int id2, int tid) {
  const int i = id2 * 256 + tid;
  if (i >= Co * Ci) return;
  const int co = i / Ci, ci = i - co * Ci;
#pragma unroll
  for (int dk = 0; dk < 3; ++dk)
    WT[((long)dk * Co + co) * Ci + ci] =
        __float2bfloat16(load_sel(W, ((long)co * Ci + ci) * 3 + dk, f));
}

__device__ void task_cvt(const void* W, bf16* O, int f, int n, int id2, int tid) {
  const int i = id2 * 256 + tid;
  if (i < n) O[i] = __float2bfloat16(load_sel(W, i, f));
}

// --- conv tile (R8-proven MFMA body, m0/n0/smem parameterized) ---
__device__ void conv_tile(
    const bf16* __restrict__ XT, const bf16* __restrict__ WT,
    const float* __restrict__ bias, void* __restrict__ Y,
    int Cin, int Cout, int T, int KW, int pad, int relu, int outmode,
    int m0, int n0, short* As, short* Bs) {
  const int K = Cin * KW;
  const int tid = threadIdx.x;
  const int wave = tid >> 6;
  const int lane = tid & 63;

  const int row = tid >> 2;          // 0..63
  const int koff = (tid & 3) * 8;    // 0,8,16,24
  const int n = n0 + row;
  const int bb = n / T;
  const int t = n - bb * T;

  const int wm = (wave >> 1) * 32;
  const int wn = (wave & 1) * 32;
  const int fm = lane & 15;
  const int quad = lane >> 4;

  f32x4 acc[2][2] = {};

  const short* ap0 = As + (wm + fm) * LDSW + quad * 8;
  const short* bp0 = Bs + (wn + fm) * LDSW + quad * 8;

  __syncthreads();  // protect LDS reuse across jobs/phases
  for (int k0 = 0; k0 < K; k0 += 32) {
    {
      const int k = k0 + koff;
      const int m = m0 + row;
      uint4 v = {0u, 0u, 0u, 0u};
      if (m < Cout && k < K) {
        const int dk = k / Cin;    // Cin%8==0 -> 8-chunk never straddles dk
        const int ci = k - dk * Cin;
        v = *(const uint4*)(WT + ((long)dk * Cout + m) * Cin + ci);
      }
      *(uint4*)(As + row * LDSW + koff) = v;
    }
    {
      const int k = k0 + koff;
      uint4 v = {0u, 0u, 0u, 0u};
      if (k < K) {
        const int dk = k / Cin;
        const int ci = k - dk * Cin;
        const int tt = t + dk - pad;
        if (tt >= 0 && tt < T)
          v = *(const uint4*)(XT + ((long)bb * T + tt) * Cin + ci);
      }
      *(uint4*)(Bs + row * LDSW + koff) = v;
    }
    __syncthreads();
    {
      bf16x8 a0 = *(const bf16x8*)(ap0);
      bf16x8 a1 = *(const bf16x8*)(ap0 + 16 * LDSW);
      bf16x8 b0 = *(const bf16x8*)(bp0);
      bf16x8 b1 = *(const bf16x8*)(bp0 + 16 * LDSW);
      acc[0][0] = __builtin_amdgcn_mfma_f32_16x16x32_bf16(a0, b0, acc[0][0], 0, 0, 0);
      acc[0][1] = __builtin_amdgcn_mfma_f32_16x16x32_bf16(a0, b1, acc[0][1], 0, 0, 0);
      acc[1][0] = __builtin_amdgcn_mfma_f32_16x16x32_bf16(a1, b0, acc[1][0], 0, 0, 0);
      acc[1][1] = __builtin_amdgcn_mfma_f32_16x16x32_bf16(a1, b1, acc[1][1], 0, 0, 0);
    }
    __syncthreads();
  }

  // Epilogue: D col(n) = lane&15, row(m) = quad*4 + reg  [m89-verified].
#pragma unroll
  for (int mi = 0; mi < 2; ++mi) {
    const int mrow = m0 + wm + mi * 16 + quad * 4;
    if (mrow >= Cout) continue;
    float bi[4];
#pragma unroll
    for (int r = 0; r < 4; ++r) bi[r] = bias[mrow + r];
#pragma unroll
    for (int ni = 0; ni < 2; ++ni) {
      const int ncol = n0 + wn + ni * 16 + fm;
      const long base = (long)ncol * Cout + mrow;
      float o[4];
#pragma unroll
      for (int r = 0; r < 4; ++r) {
        float v = acc[mi][ni][r] + bi[r];
        if (relu) v = fmaxf(v, 0.f);
        o[r] = v;
      }
      if (outmode == 0) {
        ushort4 u;
        u.x = f2bf(o[0]); u.y = f2bf(o[1]); u.z = f2bf(o[2]); u.w = f2bf(o[3]);
        *(ushort4*)((bf16*)Y + base) = u;
      } else {
        *(float4*)((float*)Y + base) = make_float4(o[0], o[1], o[2], o[3]);
      }
    }
  }
}

// --- dist for 4 consecutive t1 rows (kv loads amortized 4x) ---
__device__ void dist_quad(const float* __restrict__ qeT,
                          const float* __restrict__ keT,
                          const void* __restrict__ prior,
                          const float* __restrict__ mf, void* __restrict__ out,
                          int f, int b, int t1base, float* sq, float* red) {
  const int tid = threadIdx.x;
  __syncthreads();  // protect sq reuse across jobs
  for (int i = tid; i < 4 * CA; i += 256) {
    int u = i / CA, c = i - u * CA;
    sq[i] = qeT[((long)b * T1_ + t1base + u) * CA + c];
  }
  __syncthreads();

  const int t2 = tid;
  const bool valid = (t2 < T2_);
  float x[4] = {-INFINITY, -INFINITY, -INFINITY, -INFINITY};
  if (valid) {
    const float4* kb = (const float4*)(keT + ((long)b * T2_ + t2) * CA);
    float s[4] = {0.f, 0.f, 0.f, 0.f};
#pragma unroll 4
    for (int j = 0; j < CA / 4; ++j) {
      float4 kv = kb[j];
#pragma unroll
      for (int u = 0; u < 4; ++u) {
        float4 qv = ((const float4*)(sq + u * CA))[j];  // LDS broadcast
        float d;
        d = qv.x - kv.x; s[u] = fmaf(d, d, s[u]);
        d = qv.y - kv.y; s[u] = fmaf(d, d, s[u]);
        d = qv.z - kv.z; s[u] = fmaf(d, d, s[u]);
        d = qv.w - kv.w; s[u] = fmaf(d, d, s[u]);
      }
    }
#pragma unroll
    for (int u = 0; u < 4; ++u) x[u] = -0.0005f * s[u];
  }

  const float mval = valid ? mf[b * T2_ + t2] : 0.f;
  const long N = (long)B_ * T1_ * T2_;

  for (int u = 0; u < 4; ++u) {
    const int t1 = t1base + u;
    const float xx = x[u];

    float m = xx;
#pragma unroll
    for (int o = 32; o > 0; o >>= 1) m = fmaxf(m, __shfl_down(m, o, 64));
    if ((tid & 63) == 0) red[tid >> 6] = m;
    __syncthreads();
    const float M1 = fmaxf(fmaxf(red[0], red[1]), fmaxf(red[2], red[3]));

    float e = (xx == -INFINITY) ? 0.f : expf(xx - M1);
    float ssum = e;
#pragma unroll
    for (int o = 32; o > 0; o >>= 1) ssum += __shfl_down(ssum, o, 64);
    if ((tid & 63) == 0) red[(tid >> 6) + 4] = ssum;
    __syncthreads();
    const float S1 = red[4] + red[5] + red[6] + red[7];
    const float logZ = logf(S1);

    const long oidx = ((long)b * T1_ + t1) * T2_ + t2;
    float lp = -INFINITY;
    if (valid) {
      float pr = load_sel(prior, oidx, f);
      lp = (xx - M1 - logZ) + logf(fmaxf(pr, 0.f) + 1e-8f);
      if (f) ((float*)out)[N + oidx] = lp;
      else   ((bf16*)out)[N + oidx] = __float2bfloat16(lp);
    }

    float xm = lp;
    if (valid && mval != 0.f) xm = -INFINITY;

    __syncthreads();  // red[0..3] about to be rewritten
    float m2 = xm;
#pragma unroll
    for (int o = 32; o > 0; o >>= 1) m2 = fmaxf(m2, __shfl_down(m2, o, 64));
    if ((tid & 63) == 0) red[tid >> 6] = m2;
    __syncthreads();
    const float M2 = fmaxf(fmaxf(red[0], red[1]), fmaxf(red[2], red[3]));

    float e2 = (xm == -INFINITY) ? 0.f : expf(xm - M2);
    float s2 = e2;
#pragma unroll
    for (int o = 32; o > 0; o >>= 1) s2 += __shfl_down(s2, o, 64);
    if ((tid & 63) == 0) red[(tid >> 6) + 4] = s2;
    __syncthreads();
    const float S2 = red[4] + red[5] + red[6] + red[7];

    if (valid) {
      float a = (S2 > 0.f) ? (e2 / S2) : 0.f;
      if (f) ((float*)out)[oidx] = a;
      else   ((bf16*)out)[oidx] = __float2bfloat16(a);
    }
    __syncthreads();  // red reuse for next u
  }
}

// ---------------------------------------------------------------------------
struct MegaArgs {
  const void *queries, *keys, *mask, *prior;
  const void *kw1, *kb1, *kw2, *kb2, *qw1, *qb1, *qw2, *qb2, *qw3, *qb3;
  bf16 *keysT, *queriesT, *w1T, *qw1T, *kw2c, *qw2c, *qw3c;
  float *biasf, *mf, *keT, *qeT;
  bf16 *ke1T, *qe1T, *qe2T;
  void* out;
};

__global__ __launch_bounds__(256, 2) void k_mega(MegaArgs p) {
  __shared__ __align__(16) short sA[64 * LDSW];
  __shared__ __align__(16) short sB[64 * LDSW];
  const int tid = threadIdx.x;
  cg::grid_group grid = cg::this_grid();

  const int f = detect_f32((const unsigned short*)p.queries);

  float* b_k1 = p.biasf;
  float* b_k2 = p.biasf + 1024;
  float* b_q1 = p.biasf + 1104;
  float* b_q2 = p.biasf + 1264;
  float* b_q3 = p.biasf + 1344;

  // ================= P0: prep (3991 jobs) =================
  for (int id = blockIdx.x; id < 3991; id += gridDim.x) {
    int j = id;
    if (j < 896) { task_cvt_t(p.keys, p.keysT, f, CT, T2_, j, 7, (float*)sA, tid); continue; }
    j -= 896;
    if (j < 600) { task_cvt_t(p.queries, p.queriesT, f, CM, T1_, j, 25, (float*)sA, tid); continue; }
    j -= 600;
    if (j < 2048) { task_wt3(p.kw1, p.w1T, f, 1024, CT, j, tid); continue; }
    j -= 2048;
    if (j < 50) { task_wt3(p.qw1, p.qw1T, f, 160, CM, j, tid); continue; }
    j -= 50;
    if (j < 320) { task_cvt(p.kw2, p.kw2c, f, 80 * 1024, j, tid); continue; }
    j -= 320;
    if (j < 50) { task_cvt(p.qw2, p.qw2c, f, 80 * 160, j, tid); continue; }
    j -= 50;
    if (j < 25) { task_cvt(p.qw3, p.qw3c, f, 80 * 80, j, tid); continue; }
    j -= 25;
    if (j == 0) {
      for (int i = tid; i < 1424; i += 256) {
        float v;
        if (i < 1024)      v = load_sel(p.kb1, i, f);
        else if (i < 1104) v = load_sel(p.kb2, i - 1024, f);
        else if (i < 1264) v = load_sel(p.qb1, i - 1104, f);
        else if (i < 1344) v = load_sel(p.qb2, i - 1264, f);
        else               v = load_sel(p.qb3, i - 1344, f);
        p.biasf[i] = v;
      }
      continue;
    }
    // mask normalize (one job)
    {
      int* s_fmt = (int*)sB;
      const int nmask = B_ * T2_;
      __syncthreads();
      if (tid == 0) s_fmt[0] = 1;
      __syncthreads();
      const unsigned int* wi = (const unsigned int*)p.mask;
      const int nw = nmask / 4;
      int pri = 0;
      for (int i = tid; i < nw; i += 256) {
        unsigned int w = wi[i];
        if (w == 0u || w == 1u) continue;
        if (w == 0x3F803F80u || w == 0x00003F80u) { pri = max(pri, 2); continue; }
        if (w == 0x3F800000u) continue;
        unsigned int b0 = w & 0xFFu, b1 = (w >> 8) & 0xFFu,
                     b2 = (w >> 16) & 0xFFu, b3 = (w >> 24) & 0xFFu;
        if (b0 <= 1u && b1 <= 1u && b2 <= 1u && b3 <= 1u) pri = max(pri, 3);
        else pri = max(pri, 2);
      }
      if (pri) atomicMax(&s_fmt[0], pri);
      __syncthreads();
      const int fmt = s_fmt[0];
      for (int i = tid; i < nmask; i += 256) {
        int m;
        if (fmt == 3)      m = ((const unsigned char*)p.mask)[i] != 0;
        else if (fmt == 2) m = ((const unsigned short*)p.mask)[i] != 0;
        else               m = (wi[i] != 0u);
        p.mf[i] = (float)m;
      }
    }
  }
  grid.sync();

  // ================= P1: key conv1 (400) + q conv1 (300) =================
  for (int job = blockIdx.x; job < 700; job += gridDim.x) {
    if (job < 400)
      conv_tile(p.keysT, p.w1T, b_k1, p.ke1T, CT, 1024, T2_, 3, 1, 1, 0,
                (job / 25) * 64, (job % 25) * 64, sA, sB);
    else {
      int q = job - 400;
      conv_tile(p.queriesT, p.qw1T, b_q1, p.qe1T, CM, 160, T1_, 3, 1, 1, 0,
                (q / 100) * 64, (q % 100) * 64, sA, sB);
    }
  }
  grid.sync();

  // ================= P2: key conv2 (50) + q conv2 (200) =================
  for (int job = blockIdx.x; job < 250; job += gridDim.x) {
    if (job < 50)
      conv_tile(p.ke1T, p.kw2c, b_k2, p.keT, 1024, CA, T2_, 1, 0, 0, 1,
                (job / 25) * 64, (job % 25) * 64, sA, sB);
    else {
      int q = job - 50;
      conv_tile(p.qe1T, p.qw2c, b_q2, p.qe2T, 160, CM, T1_, 1, 0, 1, 0,
                (q / 100) * 64, (q % 100) * 64, sA, sB);
    }
  }
  grid.sync();

  // ================= P3: q conv3 (200) =================
  for (int job = blockIdx.x; job < 200; job += gridDim.x)
    conv_tile(p.qe2T, p.qw3c, b_q3, p.qeT, CM, CA, T1_, 1, 0, 0, 1,
              (job / 100) * 64, (job % 100) * 64, sA, sB);
  grid.sync();

  // ================= P4: dist (1600 jobs x 4 t1 rows) =================
  for (int job = blockIdx.x; job < 1600; job += gridDim.x) {
    const int b = job / 200;
    const int tq = job - b * 200;
    dist_quad(p.qeT, p.keT, p.prior, p.mf, p.out, f, b, tq * 4,
              (float*)sA, (float*)sB);
  }
}

// ---------------------------------------------------------------------------
extern "C" void kernel_launch(void* const* d_in, const int* in_sizes, int n_in,
                              void* d_out, int out_size, void* d_ws, size_t ws_size,
                              hipStream_t stream) {
  // ---- Workspace (~14.3 MiB; proven available) ----
  float* keT   = (float*)d_ws;            // 128,000 f  [b][200][80]
  float* qeT   = keT + 128000;            // 512,000 f  [b][800][80]
  float* mf    = qeT + 512000;            //   1,600 f
  float* biasf = mf + 1600;               //   1,424 f (+pad to 1,440)
  bf16* keysT    = (bf16*)(biasf + 1440); //   819,200  [b][200][512]
  bf16* queriesT = keysT + 819200;        //   512,000  [b][800][80]
  bf16* w1T      = queriesT + 512000;     // 1,572,864  [3][1024][512]
  bf16* qw1T     = w1T + 1572864;         //    38,400  [3][160][80]
  bf16* kw2c     = qw1T + 38400;          //    81,920  [80][1024]
  bf16* qw2c     = kw2c + 81920;          //    12,800  [80][160]
  bf16* qw3c     = qw2c + 12800;          //     6,400  [80][80]
  bf16* ke1T     = qw3c + 6400;           // 1,638,400  [1600][1024]
  bf16* qe1T     = ke1T + 1638400;        // 1,024,000  [6400][160]
  bf16* qe2T     = qe1T + 1024000;        //   512,000  [6400][80]

  MegaArgs h;
  h.queries = d_in[0];  h.keys = d_in[1];  h.mask = d_in[3];  h.prior = d_in[4];
  h.kw1 = d_in[5];  h.kb1 = d_in[6];  h.kw2 = d_in[7];  h.kb2 = d_in[8];
  h.qw1 = d_in[9];  h.qb1 = d_in[10]; h.qw2 = d_in[11]; h.qb2 = d_in[12];
  h.qw3 = d_in[13]; h.qb3 = d_in[14];
  h.keysT = keysT; h.queriesT = queriesT; h.w1T = w1T; h.qw1T = qw1T;
  h.kw2c = kw2c; h.qw2c = qw2c; h.qw3c = qw3c;
  h.biasf = biasf; h.mf = mf; h.keT = keT; h.qeT = qeT;
  h.ke1T = ke1T; h.qe1T = qe1T; h.qe2T = qe2T;
  h.out = d_out;

  void* args[] = { (void*)&h };
  hipLaunchCooperativeKernel((const void*)k_mega, dim3(NBLK), dim3(256),
                             args, 0, stream);
}

// Round 10
// 172.154 us; speedup vs baseline: 2.6743x; 2.6743x over previous
//
#include <hip/hip_runtime.h>
#include <hip/hip_bf16.h>
#include <math.h>

// Problem dims (fixed by setup_inputs)
#define B_  8
#define CM  80
#define T1_ 800
#define CT  512
#define T2_ 200
#define CA  80

using bf16 = __hip_bfloat16;
typedef __attribute__((ext_vector_type(8))) short bf16x8;
typedef __attribute__((ext_vector_type(4))) float f32x4;

#define LDSW 56
#define LDSW2 72   // BK=64 row stride (144 B: 16B-aligned; 2-way-only conflicts)

__device__ __forceinline__ float load_sel(const void* p, long idx, int isf32) {
  if (isf32) return ((const float*)p)[idx];
  return __bfloat162float(((const bf16*)p)[idx]);
}

__device__ __forceinline__ unsigned short f2bf(float x) {
  bf16 h = __float2bfloat16(x);
  return *reinterpret_cast<unsigned short*>(&h);
}

// Inline dtype probe (R8/R9-proven).
__device__ __forceinline__ int detect_f32(const unsigned short* q) {
  __shared__ int s_f;
  const int tid = threadIdx.x;
  if (tid < 64) {
    unsigned short u = q[2 * tid];
    int e = (u >> 7) & 0xFF;
    unsigned long long bal = __ballot(e < 100 || e > 154);
    if (tid == 0) s_f = (__popcll(bal) >= 16) ? 1 : 0;
  }
  __syncthreads();
  return s_f;
}

// ---------------------------------------------------------------------------
// Fused prep kernel (R8-proven verbatim).
// ---------------------------------------------------------------------------
__device__ void task_cvt_t(const void* X, bf16* XT, int f, int C, int T,
                           int id2, int tilesT, float* smem, int tid) {
  const int per_b = tilesT * ((C + 31) >> 5);
  const int b = id2 / per_b;
  const int r = id2 - b * per_b;
  const int ct = r / tilesT, tt = r - ct * tilesT;
  const int c0 = ct * 32, t0 = tt * 32;
  const int tx = tid & 31, trow = tid >> 5;
#pragma unroll
  for (int p = 0; p < 4; ++p) {
    const int cr = trow + 8 * p;
    if (c0 + cr < C && t0 + tx < T)
      smem[cr * 33 + tx] = load_sel(X, ((long)b * C + c0 + cr) * T + t0 + tx, f);
  }
  __syncthreads();
#pragma unroll
  for (int p = 0; p < 4; ++p) {
    const int tr = trow + 8 * p;
    if (t0 + tr < T && c0 + tx < C)
      XT[((long)b * T + t0 + tr) * C + c0 + tx] =
          __float2bfloat16(smem[tx * 33 + tr]);
  }
}

__device__ void task_wt3(const void* W, bf16* WT, int f, int Co, int Ci,
                         int id2, int tid) {
  const int i = id2 * 256 + tid;
  if (i >= Co * Ci) return;
  const int co = i / Ci, ci = i - co * Ci;
#pragma unroll
  for (int dk = 0; dk < 3; ++dk)
    WT[((long)dk * Co + co) * Ci + ci] =
        __float2bfloat16(load_sel(W, ((long)co * Ci + ci) * 3 + dk, f));
}

__device__ void task_cvt(const void* W, bf16* O, int f, int n, int id2, int tid) {
  const int i = id2 * 256 + tid;
  if (i < n) O[i] = __float2bfloat16(load_sel(W, i, f));
}

__global__ __launch_bounds__(256) void k_prep(
    const void* __restrict__ queries, const void* __restrict__ keys,
    const void* __restrict__ mask,
    const void* __restrict__ kp_w1, const void* __restrict__ kp_b1,
    const void* __restrict__ kp_w2, const void* __restrict__ kp_b2,
    const void* __restrict__ qp_w1, const void* __restrict__ qp_b1,
    const void* __restrict__ qp_w2, const void* __restrict__ qp_b2,
    const void* __restrict__ qp_w3, const void* __restrict__ qp_b3,
    bf16* __restrict__ keysT, bf16* __restrict__ queriesT,
    bf16* __restrict__ w1T, bf16* __restrict__ qw1T,
    bf16* __restrict__ kw2c, bf16* __restrict__ qw2c, bf16* __restrict__ qw3c,
    float* __restrict__ biasf, float* __restrict__ mf) {
  __shared__ float smem[32 * 33];
  const int tid = threadIdx.x;
  const int f = detect_f32((const unsigned short*)queries);
  int id = blockIdx.x;

  if (id < 896) { task_cvt_t(keys, keysT, f, CT, T2_, id, 7, smem, tid); return; }
  id -= 896;
  if (id < 600) { task_cvt_t(queries, queriesT, f, CM, T1_, id, 25, smem, tid); return; }
  id -= 600;
  if (id < 2048) { task_wt3(kp_w1, w1T, f, 1024, CT, id, tid); return; }
  id -= 2048;
  if (id < 50) { task_wt3(qp_w1, qw1T, f, 160, CM, id, tid); return; }
  id -= 50;
  if (id < 320) { task_cvt(kp_w2, kw2c, f, 80 * 1024, id, tid); return; }
  id -= 320;
  if (id < 50) { task_cvt(qp_w2, qw2c, f, 80 * 160, id, tid); return; }
  id -= 50;
  if (id < 25) { task_cvt(qp_w3, qw3c, f, 80 * 80, id, tid); return; }
  id -= 25;

  if (id == 0) {
    for (int i = tid; i < 1424; i += 256) {
      float v;
      if (i < 1024)      v = load_sel(kp_b1, i, f);
      else if (i < 1104) v = load_sel(kp_b2, i - 1024, f);
      else if (i < 1264) v = load_sel(qp_b1, i - 1104, f);
      else if (i < 1344) v = load_sel(qp_b2, i - 1264, f);
      else               v = load_sel(qp_b3, i - 1344, f);
      biasf[i] = v;
    }
    return;
  }

  // mask normalize (R2-proven format detection)
  {
    int* s_fmt = (int*)smem;
    const int nmask = B_ * T2_;
    if (tid == 0) s_fmt[0] = 1;
    __syncthreads();
    const unsigned int* wi = (const unsigned int*)mask;
    const int nw = nmask / 4;
    int pri = 0;
    for (int i = tid; i < nw; i += 256) {
      unsigned int w = wi[i];
      if (w == 0u || w == 1u) continue;
      if (w == 0x3F803F80u || w == 0x00003F80u) { pri = max(pri, 2); continue; }
      if (w == 0x3F800000u) continue;
      unsigned int b0 = w & 0xFFu, b1 = (w >> 8) & 0xFFu,
                   b2 = (w >> 16) & 0xFFu, b3 = (w >> 24) & 0xFFu;
      if (b0 <= 1u && b1 <= 1u && b2 <= 1u && b3 <= 1u) pri = max(pri, 3);
      else pri = max(pri, 2);
    }
    if (pri) atomicMax(&s_fmt[0], pri);
    __syncthreads();
    const int fmt = s_fmt[0];
    for (int i = tid; i < nmask; i += 256) {
      int m;
      if (fmt == 3)      m = ((const unsigned char*)mask)[i] != 0;
      else if (fmt == 2) m = ((const unsigned short*)mask)[i] != 0;
      else               m = (wi[i] != 0u);
      mf[i] = (float)m;
    }
  }
}

// ---------------------------------------------------------------------------
// Generic conv tile, BK=32 (R9-proven device function, verbatim).
// ---------------------------------------------------------------------------
__device__ void conv_tile(
    const bf16* __restrict__ XT, const bf16* __restrict__ WT,
    const float* __restrict__ bias, void* __restrict__ Y,
    int Cin, int Cout, int T, int KW, int pad, int relu, int outmode,
    int m0, int n0, short* As, short* Bs) {
  const int K = Cin * KW;
  const int tid = threadIdx.x;
  const int wave = tid >> 6;
  const int lane = tid & 63;

  const int row = tid >> 2;
  const int koff = (tid & 3) * 8;
  const int n = n0 + row;
  const int bb = n / T;
  const int t = n - bb * T;

  const int wm = (wave >> 1) * 32;
  const int wn = (wave & 1) * 32;
  const int fm = lane & 15;
  const int quad = lane >> 4;

  f32x4 acc[2][2] = {};

  const short* ap0 = As + (wm + fm) * LDSW + quad * 8;
  const short* bp0 = Bs + (wn + fm) * LDSW + quad * 8;

  for (int k0 = 0; k0 < K; k0 += 32) {
    {
      const int k = k0 + koff;
      const int m = m0 + row;
      uint4 v = {0u, 0u, 0u, 0u};
      if (m < Cout && k < K) {
        const int dk = k / Cin;
        const int ci = k - dk * Cin;
        v = *(const uint4*)(WT + ((long)dk * Cout + m) * Cin + ci);
      }
      *(uint4*)(As + row * LDSW + koff) = v;
    }
    {
      const int k = k0 + koff;
      uint4 v = {0u, 0u, 0u, 0u};
      if (k < K) {
        const int dk = k / Cin;
        const int ci = k - dk * Cin;
        const int tt = t + dk - pad;
        if (tt >= 0 && tt < T)
          v = *(const uint4*)(XT + ((long)bb * T + tt) * Cin + ci);
      }
      *(uint4*)(Bs + row * LDSW + koff) = v;
    }
    __syncthreads();
    {
      bf16x8 a0 = *(const bf16x8*)(ap0);
      bf16x8 a1 = *(const bf16x8*)(ap0 + 16 * LDSW);
      bf16x8 b0 = *(const bf16x8*)(bp0);
      bf16x8 b1 = *(const bf16x8*)(bp0 + 16 * LDSW);
      acc[0][0] = __builtin_amdgcn_mfma_f32_16x16x32_bf16(a0, b0, acc[0][0], 0, 0, 0);
      acc[0][1] = __builtin_amdgcn_mfma_f32_16x16x32_bf16(a0, b1, acc[0][1], 0, 0, 0);
      acc[1][0] = __builtin_amdgcn_mfma_f32_16x16x32_bf16(a1, b0, acc[1][0], 0, 0, 0);
      acc[1][1] = __builtin_amdgcn_mfma_f32_16x16x32_bf16(a1, b1, acc[1][1], 0, 0, 0);
    }
    __syncthreads();
  }

#pragma unroll
  for (int mi = 0; mi < 2; ++mi) {
    const int mrow = m0 + wm + mi * 16 + quad * 4;
    if (mrow >= Cout) continue;
    float bi[4];
#pragma unroll
    for (int r = 0; r < 4; ++r) bi[r] = bias[mrow + r];
#pragma unroll
    for (int ni = 0; ni < 2; ++ni) {
      const int ncol = n0 + wn + ni * 16 + fm;
      const long base = (long)ncol * Cout + mrow;
      float o[4];
#pragma unroll
      for (int r = 0; r < 4; ++r) {
        float v = acc[mi][ni][r] + bi[r];
        if (relu) v = fmaxf(v, 0.f);
        o[r] = v;
      }
      if (outmode == 0) {
        ushort4 u;
        u.x = f2bf(o[0]); u.y = f2bf(o[1]); u.z = f2bf(o[2]); u.w = f2bf(o[3]);
        *(ushort4*)((bf16*)Y + base) = u;
      } else {
        *(float4*)((float*)Y + base) = make_float4(o[0], o[1], o[2], o[3]);
      }
    }
  }
}

// ---------------------------------------------------------------------------
// Key-conv1 specialized tile: BK=64 (K=1536=24*64, M=1024, T=200, pad=1,
// relu, bf16 out). Halves barrier count vs BK=32; LDS stride LDSW2=72.
// ---------------------------------------------------------------------------
__device__ void conv_tile64_k1(
    const bf16* __restrict__ XT, const bf16* __restrict__ WT,
    const float* __restrict__ bias, bf16* __restrict__ Y,
    int m0, int n0, short* As, short* Bs) {
  const int Cin = CT, Cout = 1024, T = T2_, K = 1536;
  const int tid = threadIdx.x;
  const int wave = tid >> 6;
  const int lane = tid & 63;

  const int row = tid >> 2;          // 0..63
  const int koff = (tid & 3) * 8;    // 0,8,16,24
  const int n = n0 + row;
  const int bb = n / T;
  const int t = n - bb * T;

  const int wm = (wave >> 1) * 32;
  const int wn = (wave & 1) * 32;
  const int fm = lane & 15;
  const int quad = lane >> 4;

  f32x4 acc[2][2] = {};

  const short* ap0 = As + (wm + fm) * LDSW2 + quad * 8;
  const short* bp0 = Bs + (wn + fm) * LDSW2 + quad * 8;

  for (int k0 = 0; k0 < K; k0 += 64) {
#pragma unroll
    for (int h = 0; h < 2; ++h) {
      const int k = k0 + h * 32 + koff;   // 8-aligned; Cin%8==0 -> no dk straddle
      const int dk = k / Cin;
      const int ci = k - dk * Cin;
      // A: W'[dk][m0+row][ci..+7]  (m0+row < 1024 always)
      {
        uint4 v = *(const uint4*)(WT + ((long)dk * Cout + m0 + row) * Cin + ci);
        *(uint4*)(As + row * LDSW2 + h * 32 + koff) = v;
      }
      // B: X^T[bb][t+dk-1][ci..+7]
      {
        const int tt = t + dk - 1;
        uint4 v = {0u, 0u, 0u, 0u};
        if (tt >= 0 && tt < T)
          v = *(const uint4*)(XT + ((long)bb * T + tt) * Cin + ci);
        *(uint4*)(Bs + row * LDSW2 + h * 32 + koff) = v;
      }
    }
    __syncthreads();
#pragma unroll
    for (int h = 0; h < 2; ++h) {
      bf16x8 a0 = *(const bf16x8*)(ap0 + h * 32);
      bf16x8 a1 = *(const bf16x8*)(ap0 + 16 * LDSW2 + h * 32);
      bf16x8 b0 = *(const bf16x8*)(bp0 + h * 32);
      bf16x8 b1 = *(const bf16x8*)(bp0 + 16 * LDSW2 + h * 32);
      acc[0][0] = __builtin_amdgcn_mfma_f32_16x16x32_bf16(a0, b0, acc[0][0], 0, 0, 0);
      acc[0][1] = __builtin_amdgcn_mfma_f32_16x16x32_bf16(a0, b1, acc[0][1], 0, 0, 0);
      acc[1][0] = __builtin_amdgcn_mfma_f32_16x16x32_bf16(a1, b0, acc[1][0], 0, 0, 0);
      acc[1][1] = __builtin_amdgcn_mfma_f32_16x16x32_bf16(a1, b1, acc[1][1], 0, 0, 0);
    }
    __syncthreads();
  }

  // Epilogue (relu, bf16 [n][1024])
#pragma unroll
  for (int mi = 0; mi < 2; ++mi) {
    const int mrow = m0 + wm + mi * 16 + quad * 4;
    float bi[4];
#pragma unroll
    for (int r = 0; r < 4; ++r) bi[r] = bias[mrow + r];
#pragma unroll
    for (int ni = 0; ni < 2; ++ni) {
      const int ncol = n0 + wn + ni * 16 + fm;
      const long base = (long)ncol * Cout + mrow;
      ushort4 u;
      u.x = f2bf(fmaxf(acc[mi][ni][0] + bi[0], 0.f));
      u.y = f2bf(fmaxf(acc[mi][ni][1] + bi[1], 0.f));
      u.z = f2bf(fmaxf(acc[mi][ni][2] + bi[2], 0.f));
      u.w = f2bf(fmaxf(acc[mi][ni][3] + bi[3], 0.f));
      *(ushort4*)(Y + base) = u;
    }
  }
}

// ---------------------------------------------------------------------------
// Fused conv dispatches.
// ---------------------------------------------------------------------------
__global__ __launch_bounds__(256) void k_conv1(
    const bf16* __restrict__ keysT, const bf16* __restrict__ w1T,
    const float* __restrict__ b_k1, bf16* __restrict__ ke1T,
    const bf16* __restrict__ queriesT, const bf16* __restrict__ qw1T,
    const float* __restrict__ b_q1, bf16* __restrict__ qe1T) {
  __shared__ __align__(16) short sA[64 * LDSW2];
  __shared__ __align__(16) short sB[64 * LDSW2];
  int j = blockIdx.x;
  if (j < 400) {
    conv_tile64_k1(keysT, w1T, b_k1, ke1T, (j / 25) * 64, (j % 25) * 64, sA, sB);
  } else {
    j -= 400;
    conv_tile(queriesT, qw1T, b_q1, qe1T, CM, 160, T1_, 3, 1, 1, 0,
              (j / 100) * 64, (j % 100) * 64, sA, sB);
  }
}

__global__ __launch_bounds__(256) void k_conv2(
    const bf16* __restrict__ ke1T, const bf16* __restrict__ kw2c,
    const float* __restrict__ b_k2, float* __restrict__ keT,
    const bf16* __restrict__ qe1T, const bf16* __restrict__ qw2c,
    const float* __restrict__ b_q2, bf16* __restrict__ qe2T) {
  __shared__ __align__(16) short sA[64 * LDSW];
  __shared__ __align__(16) short sB[64 * LDSW];
  int j = blockIdx.x;
  if (j < 50) {
    conv_tile(ke1T, kw2c, b_k2, keT, 1024, CA, T2_, 1, 0, 0, 1,
              (j / 25) * 64, (j % 25) * 64, sA, sB);
  } else {
    j -= 50;
    conv_tile(qe1T, qw2c, b_q2, qe2T, 160, CM, T1_, 1, 0, 1, 0,
              (j / 100) * 64, (j % 100) * 64, sA, sB);
  }
}

__global__ __launch_bounds__(256) void k_conv3(
    const bf16* __restrict__ qe2T, const bf16* __restrict__ qw3c,
    const float* __restrict__ b_q3, float* __restrict__ qeT) {
  __shared__ __align__(16) short sA[64 * LDSW];
  __shared__ __align__(16) short sB[64 * LDSW];
  const int j = blockIdx.x;
  conv_tile(qe2T, qw3c, b_q3, qeT, CM, CA, T1_, 1, 0, 0, 1,
            (j / 100) * 64, (j % 100) * 64, sA, sB);
}

// ---------------------------------------------------------------------------
// dist: 4 t1-rows per block (R9-proven dist_quad body as standalone kernel).
// ---------------------------------------------------------------------------
__global__ __launch_bounds__(256) void k_dist(
    const float* __restrict__ qeT, const float* __restrict__ keT,
    const void* __restrict__ prior, const float* __restrict__ mf,
    void* __restrict__ out, const unsigned short* __restrict__ qprobe) {
  __shared__ float sq[4 * CA];
  __shared__ float red[8];
  const int f = detect_f32(qprobe);
  const int b = blockIdx.y;
  const int t1base = blockIdx.x * 4;
  const int tid = threadIdx.x;

  for (int i = tid; i < 4 * CA; i += 256) {
    int u = i / CA, c = i - u * CA;
    sq[i] = qeT[((long)b * T1_ + t1base + u) * CA + c];
  }
  __syncthreads();

  const int t2 = tid;
  const bool valid = (t2 < T2_);
  float x[4] = {-INFINITY, -INFINITY, -INFINITY, -INFINITY};
  if (valid) {
    const float4* kb = (const float4*)(keT + ((long)b * T2_ + t2) * CA);
    float s[4] = {0.f, 0.f, 0.f, 0.f};
#pragma unroll 4
    for (int j = 0; j < CA / 4; ++j) {
      float4 kv = kb[j];
#pragma unroll
      for (int u = 0; u < 4; ++u) {
        float4 qv = ((const float4*)(sq + u * CA))[j];
        float d;
        d = qv.x - kv.x; s[u] = fmaf(d, d, s[u]);
        d = qv.y - kv.y; s[u] = fmaf(d, d, s[u]);
        d = qv.z - kv.z; s[u] = fmaf(d, d, s[u]);
        d = qv.w - kv.w; s[u] = fmaf(d, d, s[u]);
      }
    }
#pragma unroll
    for (int u = 0; u < 4; ++u) x[u] = -0.0005f * s[u];
  }

  const float mval = valid ? mf[b * T2_ + t2] : 0.f;
  const long N = (long)B_ * T1_ * T2_;

#pragma unroll
  for (int u = 0; u < 4; ++u) {
    const int t1 = t1base + u;
    const float xx = x[u];

    float m = xx;
#pragma unroll
    for (int o = 32; o > 0; o >>= 1) m = fmaxf(m, __shfl_down(m, o, 64));
    if ((tid & 63) == 0) red[tid >> 6] = m;
    __syncthreads();
    const float M1 = fmaxf(fmaxf(red[0], red[1]), fmaxf(red[2], red[3]));

    float e = (xx == -INFINITY) ? 0.f : expf(xx - M1);
    float ssum = e;
#pragma unroll
    for (int o = 32; o > 0; o >>= 1) ssum += __shfl_down(ssum, o, 64);
    if ((tid & 63) == 0) red[(tid >> 6) + 4] = ssum;
    __syncthreads();
    const float S1 = red[4] + red[5] + red[6] + red[7];
    const float logZ = logf(S1);

    const long oidx = ((long)b * T1_ + t1) * T2_ + t2;
    float lp = -INFINITY;
    if (valid) {
      float pr = load_sel(prior, oidx, f);
      lp = (xx - M1 - logZ) + logf(fmaxf(pr, 0.f) + 1e-8f);
      if (f) ((float*)out)[N + oidx] = lp;
      else   ((bf16*)out)[N + oidx] = __float2bfloat16(lp);
    }

    float xm = lp;
    if (valid && mval != 0.f) xm = -INFINITY;

    __syncthreads();
    float m2 = xm;
#pragma unroll
    for (int o = 32; o > 0; o >>= 1) m2 = fmaxf(m2, __shfl_down(m2, o, 64));
    if ((tid & 63) == 0) red[tid >> 6] = m2;
    __syncthreads();
    const float M2 = fmaxf(fmaxf(red[0], red[1]), fmaxf(red[2], red[3]));

    float e2 = (xm == -INFINITY) ? 0.f : expf(xm - M2);
    float s2 = e2;
#pragma unroll
    for (int o = 32; o > 0; o >>= 1) s2 += __shfl_down(s2, o, 64);
    if ((tid & 63) == 0) red[(tid >> 6) + 4] = s2;
    __syncthreads();
    const float S2 = red[4] + red[5] + red[6] + red[7];

    if (valid) {
      float a = (S2 > 0.f) ? (e2 / S2) : 0.f;
      if (f) ((float*)out)[oidx] = a;
      else   ((bf16*)out)[oidx] = __float2bfloat16(a);
    }
    __syncthreads();
  }
}

// ---------------------------------------------------------------------------
extern "C" void kernel_launch(void* const* d_in, const int* in_sizes, int n_in,
                              void* d_out, int out_size, void* d_ws, size_t ws_size,
                              hipStream_t stream) {
  const void* queries = d_in[0];
  const void* keys    = d_in[1];
  const void* mask    = d_in[3];
  const void* prior   = d_in[4];
  const void* kp_w1 = d_in[5];
  const void* kp_b1 = d_in[6];
  const void* kp_w2 = d_in[7];
  const void* kp_b2 = d_in[8];
  const void* qp_w1 = d_in[9];
  const void* qp_b1 = d_in[10];
  const void* qp_w2 = d_in[11];
  const void* qp_b2 = d_in[12];
  const void* qp_w3 = d_in[13];
  const void* qp_b3 = d_in[14];

  // ---- Workspace (~14.3 MiB; proven available) ----
  float* keT   = (float*)d_ws;            // 128,000 f  [b][200][80]
  float* qeT   = keT + 128000;            // 512,000 f  [b][800][80]
  float* mf    = qeT + 512000;            //   1,600 f
  float* biasf = mf + 1600;               //   1,424 f (+pad to 1,440)
  bf16* keysT    = (bf16*)(biasf + 1440); //   819,200  [b][200][512]
  bf16* queriesT = keysT + 819200;        //   512,000  [b][800][80]
  bf16* w1T      = queriesT + 512000;     // 1,572,864  [3][1024][512]
  bf16* qw1T     = w1T + 1572864;         //    38,400  [3][160][80]
  bf16* kw2c     = qw1T + 38400;          //    81,920  [80][1024]
  bf16* qw2c     = kw2c + 81920;          //    12,800  [80][160]
  bf16* qw3c     = qw2c + 12800;          //     6,400  [80][80]
  bf16* ke1T     = qw3c + 6400;           // 1,638,400  [1600][1024]
  bf16* qe1T     = ke1T + 1638400;        // 1,024,000  [6400][160]
  bf16* qe2T     = qe1T + 1024000;        //   512,000  [6400][80]

  float* b_k1 = biasf;          // 1024
  float* b_k2 = biasf + 1024;   // 80
  float* b_q1 = biasf + 1104;   // 160
  float* b_q2 = biasf + 1264;   // 80
  float* b_q3 = biasf + 1344;   // 80

  // 1) fused prep
  k_prep<<<3991, 256, 0, stream>>>(
      queries, keys, mask,
      kp_w1, kp_b1, kp_w2, kp_b2,
      qp_w1, qp_b1, qp_w2, qp_b2, qp_w3, qp_b3,
      keysT, queriesT, w1T, qw1T, kw2c, qw2c, qw3c, biasf, mf);

  // 2) conv1 (key BK=64: 400 blocks) + (query BK=32: 300 blocks)
  k_conv1<<<700, 256, 0, stream>>>(keysT, w1T, b_k1, ke1T,
                                   queriesT, qw1T, b_q1, qe1T);

  // 3) conv2 (key: 50) + (query: 200)
  k_conv2<<<250, 256, 0, stream>>>(ke1T, kw2c, b_k2, keT,
                                   qe1T, qw2c, b_q2, qe2T);

  // 4) conv3 (query: 200)
  k_conv3<<<200, 256, 0, stream>>>(qe2T, qw3c, b_q3, qeT);

  // 5) dist (4 t1-rows per block)
  k_dist<<<dim3(200, B_), 256, 0, stream>>>(
      qeT, keT, prior, mf, d_out, (const unsigned short*)queries);
}

// Round 11
// 168.061 us; speedup vs baseline: 2.7394x; 1.0244x over previous
//
#include <hip/hip_runtime.h>
#include <hip/hip_bf16.h>
#include <math.h>

// Problem dims (fixed by setup_inputs)
#define B_  8
#define CM  80
#define T1_ 800
#define CT  512
#define T2_ 200
#define CA  80

using bf16 = __hip_bfloat16;
typedef __attribute__((ext_vector_type(8))) short bf16x8;
typedef __attribute__((ext_vector_type(4))) float f32x4;

#define LDSW 56
#define LDSW2 72    // BK=64 row stride
#define LDSW3 168   // fused conv23 stage-1 row stride (K=160)
#define LDSW4 104   // fused conv23 stage-2 row stride (K=96 padded)

__device__ __forceinline__ float load_sel(const void* p, long idx, int isf32) {
  if (isf32) return ((const float*)p)[idx];
  return __bfloat162float(((const bf16*)p)[idx]);
}

__device__ __forceinline__ unsigned short f2bf(float x) {
  bf16 h = __float2bfloat16(x);
  return *reinterpret_cast<unsigned short*>(&h);
}

// Inline dtype probe (R8-R10 proven).
__device__ __forceinline__ int detect_f32(const unsigned short* q) {
  __shared__ int s_f;
  const int tid = threadIdx.x;
  if (tid < 64) {
    unsigned short u = q[2 * tid];
    int e = (u >> 7) & 0xFF;
    unsigned long long bal = __ballot(e < 100 || e > 154);
    if (tid == 0) s_f = (__popcll(bal) >= 16) ? 1 : 0;
  }
  __syncthreads();
  return s_f;
}

// ---------------------------------------------------------------------------
// Prep tasks.
// ---------------------------------------------------------------------------
__device__ void task_cvt_t(const void* X, bf16* XT, int f, int C, int T,
                           int id2, int tilesT, float* smem, int tid) {
  const int per_b = tilesT * ((C + 31) >> 5);
  const int b = id2 / per_b;
  const int r = id2 - b * per_b;
  const int ct = r / tilesT, tt = r - ct * tilesT;
  const int c0 = ct * 32, t0 = tt * 32;
  const int tx = tid & 31, trow = tid >> 5;
#pragma unroll
  for (int p = 0; p < 4; ++p) {
    const int cr = trow + 8 * p;
    if (c0 + cr < C && t0 + tx < T)
      smem[cr * 33 + tx] = load_sel(X, ((long)b * C + c0 + cr) * T + t0 + tx, f);
  }
  __syncthreads();
#pragma unroll
  for (int p = 0; p < 4; ++p) {
    const int tr = trow + 8 * p;
    if (t0 + tr < T && c0 + tx < C)
      XT[((long)b * T + t0 + tr) * C + c0 + tx] =
          __float2bfloat16(smem[tx * 33 + tr]);
  }
}

// Vectorized (Co,Ci,3)->(3,Co,Ci): thread handles 4 consecutive ci.
__device__ void task_wt3v(const void* W, bf16* WT, int f, int Co, int Ci,
                          int id2, int tid) {
  const int i = id2 * 256 + tid;
  const int g4 = Ci >> 2;
  if (i >= Co * g4) return;
  const int co = i / g4, ci = (i - co * g4) * 4;
  const long sbase = ((long)co * Ci + ci) * 3;
  float w[12];
  if (f) {
    const float4* s = (const float4*)((const float*)W + sbase);
    float4 f0 = s[0], f1 = s[1], f2 = s[2];
    w[0]=f0.x; w[1]=f0.y; w[2]=f0.z; w[3]=f0.w; w[4]=f1.x; w[5]=f1.y;
    w[6]=f1.z; w[7]=f1.w; w[8]=f2.x; w[9]=f2.y; w[10]=f2.z; w[11]=f2.w;
  } else {
#pragma unroll
    for (int j = 0; j < 12; ++j) w[j] = load_sel(W, sbase + j, 0);
  }
#pragma unroll
  for (int dk = 0; dk < 3; ++dk) {
    ushort4 u;
    u.x = f2bf(w[0 * 3 + dk]); u.y = f2bf(w[1 * 3 + dk]);
    u.z = f2bf(w[2 * 3 + dk]); u.w = f2bf(w[3 * 3 + dk]);
    *(ushort4*)(WT + ((long)dk * Co + co) * Ci + ci) = u;
  }
}

// Vectorized elementwise convert: thread handles 4 elements.
__device__ void task_cvtv(const void* W, bf16* O, int f, int n, int id2, int tid) {
  const int i = (id2 * 256 + tid) * 4;
  if (i >= n) return;
  ushort4 u;
  if (f) {
    float4 v = *(const float4*)((const float*)W + i);
    u.x = f2bf(v.x); u.y = f2bf(v.y); u.z = f2bf(v.z); u.w = f2bf(v.w);
  } else {
    u.x = f2bf(load_sel(W, i, 0));     u.y = f2bf(load_sel(W, i + 1, 0));
    u.z = f2bf(load_sel(W, i + 2, 0)); u.w = f2bf(load_sel(W, i + 3, 0));
  }
  *(ushort4*)(O + i) = u;
}

__global__ __launch_bounds__(256) void k_prep(
    const void* __restrict__ queries, const void* __restrict__ keys,
    const void* __restrict__ mask,
    const void* __restrict__ kp_w1, const void* __restrict__ kp_b1,
    const void* __restrict__ kp_w2, const void* __restrict__ kp_b2,
    const void* __restrict__ qp_w1, const void* __restrict__ qp_b1,
    const void* __restrict__ qp_w2, const void* __restrict__ qp_b2,
    const void* __restrict__ qp_w3, const void* __restrict__ qp_b3,
    bf16* __restrict__ keysT, bf16* __restrict__ queriesT,
    bf16* __restrict__ w1T, bf16* __restrict__ qw1T,
    bf16* __restrict__ kw2c, bf16* __restrict__ qw2c, bf16* __restrict__ qw3c,
    float* __restrict__ biasf, float* __restrict__ mf) {
  __shared__ float smem[32 * 33];
  const int tid = threadIdx.x;
  const int f = detect_f32((const unsigned short*)queries);
  int id = blockIdx.x;

  if (id < 896) { task_cvt_t(keys, keysT, f, CT, T2_, id, 7, smem, tid); return; }
  id -= 896;
  if (id < 600) { task_cvt_t(queries, queriesT, f, CM, T1_, id, 25, smem, tid); return; }
  id -= 600;
  if (id < 512) { task_wt3v(kp_w1, w1T, f, 1024, CT, id, tid); return; }
  id -= 512;
  if (id < 13) { task_wt3v(qp_w1, qw1T, f, 160, CM, id, tid); return; }
  id -= 13;
  if (id < 80) { task_cvtv(kp_w2, kw2c, f, 80 * 1024, id, tid); return; }
  id -= 80;
  if (id < 13) { task_cvtv(qp_w2, qw2c, f, 80 * 160, id, tid); return; }
  id -= 13;
  if (id < 7) { task_cvtv(qp_w3, qw3c, f, 80 * 80, id, tid); return; }
  id -= 7;

  if (id == 0) {
    for (int i = tid; i < 1424; i += 256) {
      float v;
      if (i < 1024)      v = load_sel(kp_b1, i, f);
      else if (i < 1104) v = load_sel(kp_b2, i - 1024, f);
      else if (i < 1264) v = load_sel(qp_b1, i - 1104, f);
      else if (i < 1344) v = load_sel(qp_b2, i - 1264, f);
      else               v = load_sel(qp_b3, i - 1344, f);
      biasf[i] = v;
    }
    return;
  }

  // mask normalize (R2-proven format detection)
  {
    int* s_fmt = (int*)smem;
    const int nmask = B_ * T2_;
    if (tid == 0) s_fmt[0] = 1;
    __syncthreads();
    const unsigned int* wi = (const unsigned int*)mask;
    const int nw = nmask / 4;
    int pri = 0;
    for (int i = tid; i < nw; i += 256) {
      unsigned int w = wi[i];
      if (w == 0u || w == 1u) continue;
      if (w == 0x3F803F80u || w == 0x00003F80u) { pri = max(pri, 2); continue; }
      if (w == 0x3F800000u) continue;
      unsigned int b0 = w & 0xFFu, b1 = (w >> 8) & 0xFFu,
                   b2 = (w >> 16) & 0xFFu, b3 = (w >> 24) & 0xFFu;
      if (b0 <= 1u && b1 <= 1u && b2 <= 1u && b3 <= 1u) pri = max(pri, 3);
      else pri = max(pri, 2);
    }
    if (pri) atomicMax(&s_fmt[0], pri);
    __syncthreads();
    const int fmt = s_fmt[0];
    for (int i = tid; i < nmask; i += 256) {
      int m;
      if (fmt == 3)      m = ((const unsigned char*)mask)[i] != 0;
      else if (fmt == 2) m = ((const unsigned short*)mask)[i] != 0;
      else               m = (wi[i] != 0u);
      mf[i] = (float)m;
    }
  }
}

// ---------------------------------------------------------------------------
// Generic conv tile, BK=32 (R9/R10-proven, verbatim).
// ---------------------------------------------------------------------------
__device__ void conv_tile(
    const bf16* __restrict__ XT, const bf16* __restrict__ WT,
    const float* __restrict__ bias, void* __restrict__ Y,
    int Cin, int Cout, int T, int KW, int pad, int relu, int outmode,
    int m0, int n0, short* As, short* Bs) {
  const int K = Cin * KW;
  const int tid = threadIdx.x;
  const int wave = tid >> 6;
  const int lane = tid & 63;

  const int row = tid >> 2;
  const int koff = (tid & 3) * 8;
  const int n = n0 + row;
  const int bb = n / T;
  const int t = n - bb * T;

  const int wm = (wave >> 1) * 32;
  const int wn = (wave & 1) * 32;
  const int fm = lane & 15;
  const int quad = lane >> 4;

  f32x4 acc[2][2] = {};

  const short* ap0 = As + (wm + fm) * LDSW + quad * 8;
  const short* bp0 = Bs + (wn + fm) * LDSW + quad * 8;

  for (int k0 = 0; k0 < K; k0 += 32) {
    {
      const int k = k0 + koff;
      const int m = m0 + row;
      uint4 v = {0u, 0u, 0u, 0u};
      if (m < Cout && k < K) {
        const int dk = k / Cin;
        const int ci = k - dk * Cin;
        v = *(const uint4*)(WT + ((long)dk * Cout + m) * Cin + ci);
      }
      *(uint4*)(As + row * LDSW + koff) = v;
    }
    {
      const int k = k0 + koff;
      uint4 v = {0u, 0u, 0u, 0u};
      if (k < K) {
        const int dk = k / Cin;
        const int ci = k - dk * Cin;
        const int tt = t + dk - pad;
        if (tt >= 0 && tt < T)
          v = *(const uint4*)(XT + ((long)bb * T + tt) * Cin + ci);
      }
      *(uint4*)(Bs + row * LDSW + koff) = v;
    }
    __syncthreads();
    {
      bf16x8 a0 = *(const bf16x8*)(ap0);
      bf16x8 a1 = *(const bf16x8*)(ap0 + 16 * LDSW);
      bf16x8 b0 = *(const bf16x8*)(bp0);
      bf16x8 b1 = *(const bf16x8*)(bp0 + 16 * LDSW);
      acc[0][0] = __builtin_amdgcn_mfma_f32_16x16x32_bf16(a0, b0, acc[0][0], 0, 0, 0);
      acc[0][1] = __builtin_amdgcn_mfma_f32_16x16x32_bf16(a0, b1, acc[0][1], 0, 0, 0);
      acc[1][0] = __builtin_amdgcn_mfma_f32_16x16x32_bf16(a1, b0, acc[1][0], 0, 0, 0);
      acc[1][1] = __builtin_amdgcn_mfma_f32_16x16x32_bf16(a1, b1, acc[1][1], 0, 0, 0);
    }
    __syncthreads();
  }

#pragma unroll
  for (int mi = 0; mi < 2; ++mi) {
    const int mrow = m0 + wm + mi * 16 + quad * 4;
    if (mrow >= Cout) continue;
    float bi[4];
#pragma unroll
    for (int r = 0; r < 4; ++r) bi[r] = bias[mrow + r];
#pragma unroll
    for (int ni = 0; ni < 2; ++ni) {
      const int ncol = n0 + wn + ni * 16 + fm;
      const long base = (long)ncol * Cout + mrow;
      float o[4];
#pragma unroll
      for (int r = 0; r < 4; ++r) {
        float v = acc[mi][ni][r] + bi[r];
        if (relu) v = fmaxf(v, 0.f);
        o[r] = v;
      }
      if (outmode == 0) {
        ushort4 u;
        u.x = f2bf(o[0]); u.y = f2bf(o[1]); u.z = f2bf(o[2]); u.w = f2bf(o[3]);
        *(ushort4*)((bf16*)Y + base) = u;
      } else {
        *(float4*)((float*)Y + base) = make_float4(o[0], o[1], o[2], o[3]);
      }
    }
  }
}

// ---------------------------------------------------------------------------
// Key-conv1 specialized tile: BK=64 (R10-proven, verbatim).
// ---------------------------------------------------------------------------
__device__ void conv_tile64_k1(
    const bf16* __restrict__ XT, const bf16* __restrict__ WT,
    const float* __restrict__ bias, bf16* __restrict__ Y,
    int m0, int n0, short* As, short* Bs) {
  const int Cin = CT, Cout = 1024, T = T2_, K = 1536;
  const int tid = threadIdx.x;
  const int wave = tid >> 6;
  const int lane = tid & 63;

  const int row = tid >> 2;
  const int koff = (tid & 3) * 8;
  const int n = n0 + row;
  const int bb = n / T;
  const int t = n - bb * T;

  const int wm = (wave >> 1) * 32;
  const int wn = (wave & 1) * 32;
  const int fm = lane & 15;
  const int quad = lane >> 4;

  f32x4 acc[2][2] = {};

  const short* ap0 = As + (wm + fm) * LDSW2 + quad * 8;
  const short* bp0 = Bs + (wn + fm) * LDSW2 + quad * 8;

  for (int k0 = 0; k0 < K; k0 += 64) {
#pragma unroll
    for (int h = 0; h < 2; ++h) {
      const int k = k0 + h * 32 + koff;
      const int dk = k / Cin;
      const int ci = k - dk * Cin;
      {
        uint4 v = *(const uint4*)(WT + ((long)dk * Cout + m0 + row) * Cin + ci);
        *(uint4*)(As + row * LDSW2 + h * 32 + koff) = v;
      }
      {
        const int tt = t + dk - 1;
        uint4 v = {0u, 0u, 0u, 0u};
        if (tt >= 0 && tt < T)
          v = *(const uint4*)(XT + ((long)bb * T + tt) * Cin + ci);
        *(uint4*)(Bs + row * LDSW2 + h * 32 + koff) = v;
      }
    }
    __syncthreads();
#pragma unroll
    for (int h = 0; h < 2; ++h) {
      bf16x8 a0 = *(const bf16x8*)(ap0 + h * 32);
      bf16x8 a1 = *(const bf16x8*)(ap0 + 16 * LDSW2 + h * 32);
      bf16x8 b0 = *(const bf16x8*)(bp0 + h * 32);
      bf16x8 b1 = *(const bf16x8*)(bp0 + 16 * LDSW2 + h * 32);
      acc[0][0] = __builtin_amdgcn_mfma_f32_16x16x32_bf16(a0, b0, acc[0][0], 0, 0, 0);
      acc[0][1] = __builtin_amdgcn_mfma_f32_16x16x32_bf16(a0, b1, acc[0][1], 0, 0, 0);
      acc[1][0] = __builtin_amdgcn_mfma_f32_16x16x32_bf16(a1, b0, acc[1][0], 0, 0, 0);
      acc[1][1] = __builtin_amdgcn_mfma_f32_16x16x32_bf16(a1, b1, acc[1][1], 0, 0, 0);
    }
    __syncthreads();
  }

#pragma unroll
  for (int mi = 0; mi < 2; ++mi) {
    const int mrow = m0 + wm + mi * 16 + quad * 4;
    float bi[4];
#pragma unroll
    for (int r = 0; r < 4; ++r) bi[r] = bias[mrow + r];
#pragma unroll
    for (int ni = 0; ni < 2; ++ni) {
      const int ncol = n0 + wn + ni * 16 + fm;
      const long base = (long)ncol * Cout + mrow;
      ushort4 u;
      u.x = f2bf(fmaxf(acc[mi][ni][0] + bi[0], 0.f));
      u.y = f2bf(fmaxf(acc[mi][ni][1] + bi[1], 0.f));
      u.z = f2bf(fmaxf(acc[mi][ni][2] + bi[2], 0.f));
      u.w = f2bf(fmaxf(acc[mi][ni][3] + bi[3], 0.f));
      *(ushort4*)(Y + base) = u;
    }
  }
}

__global__ __launch_bounds__(256) void k_conv1(
    const bf16* __restrict__ keysT, const bf16* __restrict__ w1T,
    const float* __restrict__ b_k1, bf16* __restrict__ ke1T,
    const bf16* __restrict__ queriesT, const bf16* __restrict__ qw1T,
    const float* __restrict__ b_q1, bf16* __restrict__ qe1T) {
  __shared__ __align__(16) short sA[64 * LDSW2];
  __shared__ __align__(16) short sB[64 * LDSW2];
  int j = blockIdx.x;
  if (j < 400) {
    conv_tile64_k1(keysT, w1T, b_k1, ke1T, (j / 25) * 64, (j % 25) * 64, sA, sB);
  } else {
    j -= 400;
    conv_tile(queriesT, qw1T, b_q1, qe1T, CM, 160, T1_, 3, 1, 1, 0,
              (j / 100) * 64, (j % 100) * 64, sA, sB);
  }
}

// ---------------------------------------------------------------------------
// Fused query conv2(160->80,ReLU)+conv3(80->80) per 64-position block.
// k=1 convs are pointwise -> the chain is local to the position tile.
// Stage 1: sIn[64x160], sW2[80x160] -> 25 MFMAs -> C1 (+bias2, ReLU).
// Repack:  C1 -> sC[64x96] in B-operand layout (zero-padded K 80->96);
//          stage sW3[80x96] (zero-padded).  [m120-verified LDS round-trip]
// Stage 2: 15 MFMAs -> +bias3 -> qeT fp32 [n][80].
// ---------------------------------------------------------------------------
__device__ void conv23_tile(
    const bf16* __restrict__ qe1T, const bf16* __restrict__ qw2c,
    const float* __restrict__ b_q2, const bf16* __restrict__ qw3c,
    const float* __restrict__ b_q3, float* __restrict__ qeT,
    int n0, short* smem) {
  short* sIn = smem;                 // 64 x LDSW3 (10752 shorts)
  short* sW2 = smem + 64 * LDSW3;    // 80 x LDSW3 (13440 shorts)
  short* sC  = smem;                 // 64 x LDSW4 (6656)  [aliases sIn]
  short* sW3 = smem + 64 * LDSW3;    // 80 x LDSW4 (8320)  [aliases sW2]
  const int tid = threadIdx.x;
  const int wave = tid >> 6;
  const int lane = tid & 63;
  const int fm = lane & 15;
  const int quad = lane >> 4;

  // --- stage 1 staging ---
  // sIn: 64 rows x 160 k = 1280 uint4-chunks; thread gets 5.
#pragma unroll
  for (int c = tid; c < 1280; c += 256) {
    const int row = c / 20, kc = (c - row * 20) * 8;
    uint4 v = *(const uint4*)(qe1T + (long)(n0 + row) * 160 + kc);
    *(uint4*)(sIn + row * LDSW3 + kc) = v;
  }
  // sW2: 80 x 160 = 1600 chunks.
  for (int c = tid; c < 1600; c += 256) {
    const int row = c / 20, kc = (c - row * 20) * 8;
    uint4 v = *(const uint4*)(qw2c + (long)row * 160 + kc);
    *(uint4*)(sW2 + row * LDSW3 + kc) = v;
  }
  __syncthreads();

  // --- stage 1 compute: wave w covers positions 16w..16w+15, full M=80 ---
  f32x4 acc1[5] = {};
#pragma unroll
  for (int ks = 0; ks < 5; ++ks) {
    bf16x8 b = *(const bf16x8*)(sIn + (16 * wave + fm) * LDSW3 + ks * 32 + quad * 8);
#pragma unroll
    for (int mt = 0; mt < 5; ++mt) {
      bf16x8 a = *(const bf16x8*)(sW2 + (16 * mt + fm) * LDSW3 + ks * 32 + quad * 8);
      acc1[mt] = __builtin_amdgcn_mfma_f32_16x16x32_bf16(a, b, acc1[mt], 0, 0, 0);
    }
  }
  __syncthreads();  // all reads of sIn/sW2 done before aliasing writes

  // --- repack C1 (bias2 + ReLU) into sC; stage sW3; zero pads ---
#pragma unroll
  for (int mt = 0; mt < 5; ++mt) {
    const int ch = 16 * mt + quad * 4;
    const float4 b2 = *(const float4*)(b_q2 + ch);
    ushort4 u;
    u.x = f2bf(fmaxf(acc1[mt][0] + b2.x, 0.f));
    u.y = f2bf(fmaxf(acc1[mt][1] + b2.y, 0.f));
    u.z = f2bf(fmaxf(acc1[mt][2] + b2.z, 0.f));
    u.w = f2bf(fmaxf(acc1[mt][3] + b2.w, 0.f));
    *(ushort4*)(sC + (16 * wave + fm) * LDSW4 + ch) = u;
  }
  // zero-pad sC k=80..95 (64 rows x 2 chunks)
  if (tid < 128) {
    const int row = tid >> 1, off = 80 + (tid & 1) * 8;
    uint4 z = {0u, 0u, 0u, 0u};
    *(uint4*)(sC + row * LDSW4 + off) = z;
  }
  // sW3: 80 x 80 = 800 chunks
  for (int c = tid; c < 800; c += 256) {
    const int row = c / 10, kc = (c - row * 10) * 8;
    uint4 v = *(const uint4*)(qw3c + (long)row * 80 + kc);
    *(uint4*)(sW3 + row * LDSW4 + kc) = v;
  }
  // zero-pad sW3 k=80..95 (80 rows x 2 chunks)
  if (tid < 160) {
    const int row = tid >> 1, off = 80 + (tid & 1) * 8;
    uint4 z = {0u, 0u, 0u, 0u};
    *(uint4*)(sW3 + row * LDSW4 + off) = z;
  }
  __syncthreads();

  // --- stage 2 compute: K=96 (3 steps) ---
  f32x4 acc2[5] = {};
#pragma unroll
  for (int ks = 0; ks < 3; ++ks) {
    bf16x8 b = *(const bf16x8*)(sC + (16 * wave + fm) * LDSW4 + ks * 32 + quad * 8);
#pragma unroll
    for (int mt = 0; mt < 5; ++mt) {
      bf16x8 a = *(const bf16x8*)(sW3 + (16 * mt + fm) * LDSW4 + ks * 32 + quad * 8);
      acc2[mt] = __builtin_amdgcn_mfma_f32_16x16x32_bf16(a, b, acc2[mt], 0, 0, 0);
    }
  }

  // --- epilogue: qeT fp32 [n][80] ---
  const int pos = n0 + 16 * wave + fm;
#pragma unroll
  for (int mt = 0; mt < 5; ++mt) {
    const int ch = 16 * mt + quad * 4;
    const float4 b3 = *(const float4*)(b_q3 + ch);
    float4 o = make_float4(acc2[mt][0] + b3.x, acc2[mt][1] + b3.y,
                           acc2[mt][2] + b3.z, acc2[mt][3] + b3.w);
    *(float4*)(qeT + (long)pos * CA + ch) = o;
  }
}

__global__ __launch_bounds__(256) void k_conv2f(
    const bf16* __restrict__ ke1T, const bf16* __restrict__ kw2c,
    const float* __restrict__ b_k2, float* __restrict__ keT,
    const bf16* __restrict__ qe1T, const bf16* __restrict__ qw2c,
    const float* __restrict__ b_q2, const bf16* __restrict__ qw3c,
    const float* __restrict__ b_q3, float* __restrict__ qeT) {
  __shared__ __align__(16) short smem[64 * LDSW3 + 80 * LDSW3];  // 24192 shorts
  int j = blockIdx.x;
  if (j < 50) {
    conv_tile(ke1T, kw2c, b_k2, keT, 1024, CA, T2_, 1, 0, 0, 1,
              (j / 25) * 64, (j % 25) * 64, smem, smem + 64 * LDSW);
  } else {
    conv23_tile(qe1T, qw2c, b_q2, qw3c, b_q3, qeT, (j - 50) * 64, smem);
  }
}

// ---------------------------------------------------------------------------
// dist: 4 t1-rows per block, reductions ILP'd across rows (5 barriers total).
// ---------------------------------------------------------------------------
__global__ __launch_bounds__(256) void k_dist(
    const float* __restrict__ qeT, const float* __restrict__ keT,
    const void* __restrict__ prior, const float* __restrict__ mf,
    void* __restrict__ out, const unsigned short* __restrict__ qprobe) {
  __shared__ float sq[4 * CA];
  __shared__ float redA[16], redB[16], redC[16], redD[16];
  const int f = detect_f32(qprobe);
  const int b = blockIdx.y;
  const int t1base = blockIdx.x * 4;
  const int tid = threadIdx.x;
  const int wid = tid >> 6;

  for (int i = tid; i < 4 * CA; i += 256) {
    int u = i / CA, c = i - u * CA;
    sq[i] = qeT[((long)b * T1_ + t1base + u) * CA + c];
  }
  __syncthreads();

  const int t2 = tid;
  const bool valid = (t2 < T2_);
  float x[4] = {-INFINITY, -INFINITY, -INFINITY, -INFINITY};
  if (valid) {
    const float4* kb = (const float4*)(keT + ((long)b * T2_ + t2) * CA);
    float s[4] = {0.f, 0.f, 0.f, 0.f};
#pragma unroll 4
    for (int j = 0; j < CA / 4; ++j) {
      float4 kv = kb[j];
#pragma unroll
      for (int u = 0; u < 4; ++u) {
        float4 qv = ((const float4*)(sq + u * CA))[j];
        float d;
        d = qv.x - kv.x; s[u] = fmaf(d, d, s[u]);
        d = qv.y - kv.y; s[u] = fmaf(d, d, s[u]);
        d = qv.z - kv.z; s[u] = fmaf(d, d, s[u]);
        d = qv.w - kv.w; s[u] = fmaf(d, d, s[u]);
      }
    }
#pragma unroll
    for (int u = 0; u < 4; ++u) x[u] = -0.0005f * s[u];
  }

  const float mval = valid ? mf[b * T2_ + t2] : 0.f;
  const long N = (long)B_ * T1_ * T2_;

  // --- phase 1: row maxima (ILP across u) ---
  float m[4] = {x[0], x[1], x[2], x[3]};
#pragma unroll
  for (int o = 32; o > 0; o >>= 1)
#pragma unroll
    for (int u = 0; u < 4; ++u) m[u] = fmaxf(m[u], __shfl_down(m[u], o, 64));
  if ((tid & 63) == 0)
#pragma unroll
    for (int u = 0; u < 4; ++u) redA[wid * 4 + u] = m[u];
  __syncthreads();
  float M1[4];
#pragma unroll
  for (int u = 0; u < 4; ++u)
    M1[u] = fmaxf(fmaxf(redA[u], redA[4 + u]), fmaxf(redA[8 + u], redA[12 + u]));

  // --- phase 2: sum of exp ---
  float e[4], s1[4];
#pragma unroll
  for (int u = 0; u < 4; ++u) {
    e[u] = (x[u] == -INFINITY) ? 0.f : expf(x[u] - M1[u]);
    s1[u] = e[u];
  }
#pragma unroll
  for (int o = 32; o > 0; o >>= 1)
#pragma unroll
    for (int u = 0; u < 4; ++u) s1[u] += __shfl_down(s1[u], o, 64);
  if ((tid & 63) == 0)
#pragma unroll
    for (int u = 0; u < 4; ++u) redB[wid * 4 + u] = s1[u];
  __syncthreads();
  float lp[4];
#pragma unroll
  for (int u = 0; u < 4; ++u) {
    const float S1 = redB[u] + redB[4 + u] + redB[8 + u] + redB[12 + u];
    const float logZ = logf(S1);
    lp[u] = -INFINITY;
    if (valid) {
      const long oidx = ((long)b * T1_ + t1base + u) * T2_ + t2;
      float pr = load_sel(prior, oidx, f);
      lp[u] = (x[u] - M1[u] - logZ) + logf(fmaxf(pr, 0.f) + 1e-8f);
      if (f) ((float*)out)[N + oidx] = lp[u];
      else   ((bf16*)out)[N + oidx] = __float2bfloat16(lp[u]);
    }
  }

  // --- phase 3: masked maxima ---
  float xm[4], m2[4];
#pragma unroll
  for (int u = 0; u < 4; ++u) {
    xm[u] = (valid && mval != 0.f) ? -INFINITY : lp[u];
    m2[u] = xm[u];
  }
#pragma unroll
  for (int o = 32; o > 0; o >>= 1)
#pragma unroll
    for (int u = 0; u < 4; ++u) m2[u] = fmaxf(m2[u], __shfl_down(m2[u], o, 64));
  if ((tid & 63) == 0)
#pragma unroll
    for (int u = 0; u < 4; ++u) redC[wid * 4 + u] = m2[u];
  __syncthreads();
  float M2[4];
#pragma unroll
  for (int u = 0; u < 4; ++u)
    M2[u] = fmaxf(fmaxf(redC[u], redC[4 + u]), fmaxf(redC[8 + u], redC[12 + u]));

  // --- phase 4: masked sum + final write ---
  float e2[4], s2[4];
#pragma unroll
  for (int u = 0; u < 4; ++u) {
    e2[u] = (xm[u] == -INFINITY) ? 0.f : expf(xm[u] - M2[u]);
    s2[u] = e2[u];
  }
#pragma unroll
  for (int o = 32; o > 0; o >>= 1)
#pragma unroll
    for (int u = 0; u < 4; ++u) s2[u] += __shfl_down(s2[u], o, 64);
  if ((tid & 63) == 0)
#pragma unroll
    for (int u = 0; u < 4; ++u) redD[wid * 4 + u] = s2[u];
  __syncthreads();
#pragma unroll
  for (int u = 0; u < 4; ++u) {
    const float S2 = redD[u] + redD[4 + u] + redD[8 + u] + redD[12 + u];
    if (valid) {
      float a = (S2 > 0.f) ? (e2[u] / S2) : 0.f;
      const long oidx = ((long)b * T1_ + t1base + u) * T2_ + t2;
      if (f) ((float*)out)[oidx] = a;
      else   ((bf16*)out)[oidx] = __float2bfloat16(a);
    }
  }
}

// ---------------------------------------------------------------------------
extern "C" void kernel_launch(void* const* d_in, const int* in_sizes, int n_in,
                              void* d_out, int out_size, void* d_ws, size_t ws_size,
                              hipStream_t stream) {
  const void* queries = d_in[0];
  const void* keys    = d_in[1];
  const void* mask    = d_in[3];
  const void* prior   = d_in[4];
  const void* kp_w1 = d_in[5];
  const void* kp_b1 = d_in[6];
  const void* kp_w2 = d_in[7];
  const void* kp_b2 = d_in[8];
  const void* qp_w1 = d_in[9];
  const void* qp_b1 = d_in[10];
  const void* qp_w2 = d_in[11];
  const void* qp_b2 = d_in[12];
  const void* qp_w3 = d_in[13];
  const void* qp_b3 = d_in[14];

  // ---- Workspace (proven layout) ----
  float* keT   = (float*)d_ws;            // 128,000 f  [b][200][80]
  float* qeT   = keT + 128000;            // 512,000 f  [b][800][80]
  float* mf    = qeT + 512000;            //   1,600 f
  float* biasf = mf + 1600;               //   1,424 f (+pad to 1,440)
  bf16* keysT    = (bf16*)(biasf + 1440); //   819,200  [b][200][512]
  bf16* queriesT = keysT + 819200;        //   512,000  [b][800][80]
  bf16* w1T      = queriesT + 512000;     // 1,572,864  [3][1024][512]
  bf16* qw1T     = w1T + 1572864;         //    38,400  [3][160][80]
  bf16* kw2c     = qw1T + 38400;          //    81,920  [80][1024]
  bf16* qw2c     = kw2c + 81920;          //    12,800  [80][160]
  bf16* qw3c     = qw2c + 12800;          //     6,400  [80][80]
  bf16* ke1T     = qw3c + 6400;           // 1,638,400  [1600][1024]
  bf16* qe1T     = ke1T + 1638400;        // 1,024,000  [6400][160]

  float* b_k1 = biasf;          // 1024
  float* b_k2 = biasf + 1024;   // 80
  float* b_q1 = biasf + 1104;   // 160
  float* b_q2 = biasf + 1264;   // 80
  float* b_q3 = biasf + 1344;   // 80

  // 1) fused prep: 896+600+512+13+80+13+7+1+1 = 2123 blocks
  k_prep<<<2123, 256, 0, stream>>>(
      queries, keys, mask,
      kp_w1, kp_b1, kp_w2, kp_b2,
      qp_w1, qp_b1, qp_w2, qp_b2, qp_w3, qp_b3,
      keysT, queriesT, w1T, qw1T, kw2c, qw2c, qw3c, biasf, mf);

  // 2) conv1: key BK=64 (400) + query BK=32 (300)
  k_conv1<<<700, 256, 0, stream>>>(keysT, w1T, b_k1, ke1T,
                                   queriesT, qw1T, b_q1, qe1T);

  // 3) key conv2 (50) + fused query conv2+3 (100)
  k_conv2f<<<150, 256, 0, stream>>>(ke1T, kw2c, b_k2, keT,
                                    qe1T, qw2c, b_q2, qw3c, b_q3, qeT);

  // 4) dist
  k_dist<<<dim3(200, B_), 256, 0, stream>>>(
      qeT, keT, prior, mf, d_out, (const unsigned short*)queries);
}

// Round 12
// 167.639 us; speedup vs baseline: 2.7463x; 1.0025x over previous
//
#include <hip/hip_runtime.h>
#include <hip/hip_bf16.h>
#include <math.h>

// Problem dims (fixed by setup_inputs)
#define B_  8
#define CM  80
#define T1_ 800
#define CT  512
#define T2_ 200
#define CA  80

using bf16 = __hip_bfloat16;
typedef __attribute__((ext_vector_type(8))) short bf16x8;
typedef __attribute__((ext_vector_type(4))) float f32x4;

#define LDSW 56
#define LDSW2 72    // BK=64 row stride
#define LDSW3 168   // fused conv23 stage-1 row stride (K=160)
#define LDSW4 104   // fused conv23 stage-2 row stride (K=96 padded)

__device__ __forceinline__ float load_sel(const void* p, long idx, int isf32) {
  if (isf32) return ((const float*)p)[idx];
  return __bfloat162float(((const bf16*)p)[idx]);
}

__device__ __forceinline__ unsigned short f2bf(float x) {
  bf16 h = __float2bfloat16(x);
  return *reinterpret_cast<unsigned short*>(&h);
}

// Inline dtype probe (R8-R11 proven).
__device__ __forceinline__ int detect_f32(const unsigned short* q) {
  __shared__ int s_f;
  const int tid = threadIdx.x;
  if (tid < 64) {
    unsigned short u = q[2 * tid];
    int e = (u >> 7) & 0xFF;
    unsigned long long bal = __ballot(e < 100 || e > 154);
    if (tid == 0) s_f = (__popcll(bal) >= 16) ? 1 : 0;
  }
  __syncthreads();
  return s_f;
}

// ---------------------------------------------------------------------------
// Prep tasks (R11-proven).
// ---------------------------------------------------------------------------
__device__ void task_cvt_t(const void* X, bf16* XT, int f, int C, int T,
                           int id2, int tilesT, float* smem, int tid) {
  const int per_b = tilesT * ((C + 31) >> 5);
  const int b = id2 / per_b;
  const int r = id2 - b * per_b;
  const int ct = r / tilesT, tt = r - ct * tilesT;
  const int c0 = ct * 32, t0 = tt * 32;
  const int tx = tid & 31, trow = tid >> 5;
#pragma unroll
  for (int p = 0; p < 4; ++p) {
    const int cr = trow + 8 * p;
    if (c0 + cr < C && t0 + tx < T)
      smem[cr * 33 + tx] = load_sel(X, ((long)b * C + c0 + cr) * T + t0 + tx, f);
  }
  __syncthreads();
#pragma unroll
  for (int p = 0; p < 4; ++p) {
    const int tr = trow + 8 * p;
    if (t0 + tr < T && c0 + tx < C)
      XT[((long)b * T + t0 + tr) * C + c0 + tx] =
          __float2bfloat16(smem[tx * 33 + tr]);
  }
}

__device__ void task_wt3v(const void* W, bf16* WT, int f, int Co, int Ci,
                          int id2, int tid) {
  const int i = id2 * 256 + tid;
  const int g4 = Ci >> 2;
  if (i >= Co * g4) return;
  const int co = i / g4, ci = (i - co * g4) * 4;
  const long sbase = ((long)co * Ci + ci) * 3;
  float w[12];
  if (f) {
    const float4* s = (const float4*)((const float*)W + sbase);
    float4 f0 = s[0], f1 = s[1], f2 = s[2];
    w[0]=f0.x; w[1]=f0.y; w[2]=f0.z; w[3]=f0.w; w[4]=f1.x; w[5]=f1.y;
    w[6]=f1.z; w[7]=f1.w; w[8]=f2.x; w[9]=f2.y; w[10]=f2.z; w[11]=f2.w;
  } else {
#pragma unroll
    for (int j = 0; j < 12; ++j) w[j] = load_sel(W, sbase + j, 0);
  }
#pragma unroll
  for (int dk = 0; dk < 3; ++dk) {
    ushort4 u;
    u.x = f2bf(w[0 * 3 + dk]); u.y = f2bf(w[1 * 3 + dk]);
    u.z = f2bf(w[2 * 3 + dk]); u.w = f2bf(w[3 * 3 + dk]);
    *(ushort4*)(WT + ((long)dk * Co + co) * Ci + ci) = u;
  }
}

__device__ void task_cvtv(const void* W, bf16* O, int f, int n, int id2, int tid) {
  const int i = (id2 * 256 + tid) * 4;
  if (i >= n) return;
  ushort4 u;
  if (f) {
    float4 v = *(const float4*)((const float*)W + i);
    u.x = f2bf(v.x); u.y = f2bf(v.y); u.z = f2bf(v.z); u.w = f2bf(v.w);
  } else {
    u.x = f2bf(load_sel(W, i, 0));     u.y = f2bf(load_sel(W, i + 1, 0));
    u.z = f2bf(load_sel(W, i + 2, 0)); u.w = f2bf(load_sel(W, i + 3, 0));
  }
  *(ushort4*)(O + i) = u;
}

__global__ __launch_bounds__(256) void k_prep(
    const void* __restrict__ queries, const void* __restrict__ keys,
    const void* __restrict__ mask,
    const void* __restrict__ kp_w1, const void* __restrict__ kp_b1,
    const void* __restrict__ kp_w2, const void* __restrict__ kp_b2,
    const void* __restrict__ qp_w1, const void* __restrict__ qp_b1,
    const void* __restrict__ qp_w2, const void* __restrict__ qp_b2,
    const void* __restrict__ qp_w3, const void* __restrict__ qp_b3,
    bf16* __restrict__ keysT, bf16* __restrict__ queriesT,
    bf16* __restrict__ w1T, bf16* __restrict__ qw1T,
    bf16* __restrict__ kw2c, bf16* __restrict__ qw2c, bf16* __restrict__ qw3c,
    float* __restrict__ biasf, float* __restrict__ mf, float* __restrict__ kn) {
  __shared__ float smem[32 * 33];
  const int tid = threadIdx.x;
  const int f = detect_f32((const unsigned short*)queries);
  int id = blockIdx.x;

  if (id < 896) { task_cvt_t(keys, keysT, f, CT, T2_, id, 7, smem, tid); return; }
  id -= 896;
  if (id < 600) { task_cvt_t(queries, queriesT, f, CM, T1_, id, 25, smem, tid); return; }
  id -= 600;
  if (id < 512) { task_wt3v(kp_w1, w1T, f, 1024, CT, id, tid); return; }
  id -= 512;
  if (id < 13) { task_wt3v(qp_w1, qw1T, f, 160, CM, id, tid); return; }
  id -= 13;
  if (id < 80) { task_cvtv(kp_w2, kw2c, f, 80 * 1024, id, tid); return; }
  id -= 80;
  if (id < 13) { task_cvtv(qp_w2, qw2c, f, 80 * 160, id, tid); return; }
  id -= 13;
  if (id < 7) { task_cvtv(qp_w3, qw3c, f, 80 * 80, id, tid); return; }
  id -= 7;

  if (id == 0) {
    for (int i = tid; i < 1424; i += 256) {
      float v;
      if (i < 1024)      v = load_sel(kp_b1, i, f);
      else if (i < 1104) v = load_sel(kp_b2, i - 1024, f);
      else if (i < 1264) v = load_sel(qp_b1, i - 1104, f);
      else if (i < 1344) v = load_sel(qp_b2, i - 1264, f);
      else               v = load_sel(qp_b3, i - 1344, f);
      biasf[i] = v;
    }
    // zero key-norm accumulator (conv2 atomically accumulates into it)
    for (int i = tid; i < B_ * T2_; i += 256) kn[i] = 0.f;
    return;
  }

  // mask normalize (R2-proven format detection)
  {
    int* s_fmt = (int*)smem;
    const int nmask = B_ * T2_;
    if (tid == 0) s_fmt[0] = 1;
    __syncthreads();
    const unsigned int* wi = (const unsigned int*)mask;
    const int nw = nmask / 4;
    int pri = 0;
    for (int i = tid; i < nw; i += 256) {
      unsigned int w = wi[i];
      if (w == 0u || w == 1u) continue;
      if (w == 0x3F803F80u || w == 0x00003F80u) { pri = max(pri, 2); continue; }
      if (w == 0x3F800000u) continue;
      unsigned int b0 = w & 0xFFu, b1 = (w >> 8) & 0xFFu,
                   b2 = (w >> 16) & 0xFFu, b3 = (w >> 24) & 0xFFu;
      if (b0 <= 1u && b1 <= 1u && b2 <= 1u && b3 <= 1u) pri = max(pri, 3);
      else pri = max(pri, 2);
    }
    if (pri) atomicMax(&s_fmt[0], pri);
    __syncthreads();
    const int fmt = s_fmt[0];
    for (int i = tid; i < nmask; i += 256) {
      int m;
      if (fmt == 3)      m = ((const unsigned char*)mask)[i] != 0;
      else if (fmt == 2) m = ((const unsigned short*)mask)[i] != 0;
      else               m = (wi[i] != 0u);
      mf[i] = (float)m;
    }
  }
}

// ---------------------------------------------------------------------------
// Generic conv tile, BK=32 (proven). outmode: 0 = bf16 [n][Cout];
// 1 = fp32 [n][Cout]; 2 = keT [b][80][200] = -2v + atomicAdd v^2 into Y2.
// ---------------------------------------------------------------------------
__device__ void conv_tile(
    const bf16* __restrict__ XT, const bf16* __restrict__ WT,
    const float* __restrict__ bias, void* __restrict__ Y,
    int Cin, int Cout, int T, int KW, int pad, int relu, int outmode,
    int m0, int n0, short* As, short* Bs, float* Y2 = nullptr) {
  const int K = Cin * KW;
  const int tid = threadIdx.x;
  const int wave = tid >> 6;
  const int lane = tid & 63;

  const int row = tid >> 2;
  const int koff = (tid & 3) * 8;
  const int n = n0 + row;
  const int bb = n / T;
  const int t = n - bb * T;

  const int wm = (wave >> 1) * 32;
  const int wn = (wave & 1) * 32;
  const int fm = lane & 15;
  const int quad = lane >> 4;

  f32x4 acc[2][2] = {};

  const short* ap0 = As + (wm + fm) * LDSW + quad * 8;
  const short* bp0 = Bs + (wn + fm) * LDSW + quad * 8;

  for (int k0 = 0; k0 < K; k0 += 32) {
    {
      const int k = k0 + koff;
      const int m = m0 + row;
      uint4 v = {0u, 0u, 0u, 0u};
      if (m < Cout && k < K) {
        const int dk = k / Cin;
        const int ci = k - dk * Cin;
        v = *(const uint4*)(WT + ((long)dk * Cout + m) * Cin + ci);
      }
      *(uint4*)(As + row * LDSW + koff) = v;
    }
    {
      const int k = k0 + koff;
      uint4 v = {0u, 0u, 0u, 0u};
      if (k < K) {
        const int dk = k / Cin;
        const int ci = k - dk * Cin;
        const int tt = t + dk - pad;
        if (tt >= 0 && tt < T)
          v = *(const uint4*)(XT + ((long)bb * T + tt) * Cin + ci);
      }
      *(uint4*)(Bs + row * LDSW + koff) = v;
    }
    __syncthreads();
    {
      bf16x8 a0 = *(const bf16x8*)(ap0);
      bf16x8 a1 = *(const bf16x8*)(ap0 + 16 * LDSW);
      bf16x8 b0 = *(const bf16x8*)(bp0);
      bf16x8 b1 = *(const bf16x8*)(bp0 + 16 * LDSW);
      acc[0][0] = __builtin_amdgcn_mfma_f32_16x16x32_bf16(a0, b0, acc[0][0], 0, 0, 0);
      acc[0][1] = __builtin_amdgcn_mfma_f32_16x16x32_bf16(a0, b1, acc[0][1], 0, 0, 0);
      acc[1][0] = __builtin_amdgcn_mfma_f32_16x16x32_bf16(a1, b0, acc[1][0], 0, 0, 0);
      acc[1][1] = __builtin_amdgcn_mfma_f32_16x16x32_bf16(a1, b1, acc[1][1], 0, 0, 0);
    }
    __syncthreads();
  }

#pragma unroll
  for (int mi = 0; mi < 2; ++mi) {
    const int mrow = m0 + wm + mi * 16 + quad * 4;
    if (mrow >= Cout) continue;
    float bi[4];
#pragma unroll
    for (int r = 0; r < 4; ++r) bi[r] = bias[mrow + r];
#pragma unroll
    for (int ni = 0; ni < 2; ++ni) {
      const int ncol = n0 + wn + ni * 16 + fm;
      float o[4];
#pragma unroll
      for (int r = 0; r < 4; ++r) {
        float v = acc[mi][ni][r] + bi[r];
        if (relu) v = fmaxf(v, 0.f);
        o[r] = v;
      }
      if (outmode == 0) {
        ushort4 u;
        u.x = f2bf(o[0]); u.y = f2bf(o[1]); u.z = f2bf(o[2]); u.w = f2bf(o[3]);
        *(ushort4*)((bf16*)Y + (long)ncol * Cout + mrow) = u;
      } else if (outmode == 1) {
        *(float4*)((float*)Y + (long)ncol * Cout + mrow) =
            make_float4(o[0], o[1], o[2], o[3]);
      } else {
        // keT [b][Cout][T] = -2v, channel-major for coalesced dist reads
        const int bb2 = ncol / T;
        const int tloc = ncol - bb2 * T;
        float s4 = 0.f;
#pragma unroll
        for (int r = 0; r < 4; ++r) {
          ((float*)Y)[((long)bb2 * Cout + mrow + r) * T + tloc] = -2.f * o[r];
          s4 = fmaf(o[r], o[r], s4);
        }
        atomicAdd(&Y2[ncol], s4);
      }
    }
  }
}

// ---------------------------------------------------------------------------
// Key-conv1: 128x64 tile, BK=64. 16 MFMAs per barrier-pair (2x R10/R11).
// K=1536; BK-64 tile never straddles dk (512%64==0). 200 blocks.
// ---------------------------------------------------------------------------
__device__ void conv_tile128(
    const bf16* __restrict__ XT, const bf16* __restrict__ WT,
    const float* __restrict__ bias, bf16* __restrict__ Y,
    int m0, int n0, short* As, short* Bs) {
  const int Cin = CT, Cout = 1024, T = T2_, K = 1536;
  const int tid = threadIdx.x;
  const int wave = tid >> 6;
  const int lane = tid & 63;

  // B staging: row_b = tid>>2 (0..63)
  const int rowb = tid >> 2;
  const int nb = n0 + rowb;
  const int bbb = nb / T;
  const int tb = nb - bbb * T;

  const int wm = (wave >> 1) * 64;   // 0 or 64
  const int wn = (wave & 1) * 32;    // 0 or 32
  const int fm = lane & 15;
  const int quad = lane >> 4;

  f32x4 acc[4][2] = {};

  const short* ap0 = As + (wm + fm) * LDSW2 + quad * 8;
  const short* bp0 = Bs + (wn + fm) * LDSW2 + quad * 8;

  for (int k0 = 0; k0 < K; k0 += 64) {
    const int dk = k0 >> 9;            // constant within tile
    const int ci0 = k0 & 511;
    // A: 128 rows x 8 chunks = 1024 chunks, 4/thread (row = tid>>1)
    {
      const int arow = tid >> 1;
      const bf16* src = WT + ((long)dk * Cout + m0 + arow) * Cin + ci0 + (tid & 1) * 32;
      short* dst = As + arow * LDSW2 + (tid & 1) * 32;
#pragma unroll
      for (int hh = 0; hh < 4; ++hh)
        *(uint4*)(dst + hh * 8) = *(const uint4*)(src + hh * 8);
    }
    // B: 64 rows x 8 chunks = 512 chunks, 2/thread
    {
      const int tt = tb + dk - 1;
      const int kc0 = (tid & 3) * 16;
      if (tt >= 0 && tt < T) {
        const bf16* src = XT + ((long)bbb * T + tt) * Cin + ci0 + kc0;
        short* dst = Bs + rowb * LDSW2 + kc0;
        *(uint4*)(dst) = *(const uint4*)(src);
        *(uint4*)(dst + 8) = *(const uint4*)(src + 8);
      } else {
        uint4 z = {0u, 0u, 0u, 0u};
        short* dst = Bs + rowb * LDSW2 + kc0;
        *(uint4*)(dst) = z;
        *(uint4*)(dst + 8) = z;
      }
    }
    __syncthreads();
#pragma unroll
    for (int h = 0; h < 2; ++h) {
      bf16x8 b0 = *(const bf16x8*)(bp0 + h * 32);
      bf16x8 b1 = *(const bf16x8*)(bp0 + 16 * LDSW2 + h * 32);
#pragma unroll
      for (int mi = 0; mi < 4; ++mi) {
        bf16x8 a = *(const bf16x8*)(ap0 + mi * 16 * LDSW2 + h * 32);
        acc[mi][0] = __builtin_amdgcn_mfma_f32_16x16x32_bf16(a, b0, acc[mi][0], 0, 0, 0);
        acc[mi][1] = __builtin_amdgcn_mfma_f32_16x16x32_bf16(a, b1, acc[mi][1], 0, 0, 0);
      }
    }
    __syncthreads();
  }

#pragma unroll
  for (int mi = 0; mi < 4; ++mi) {
    const int mrow = m0 + wm + mi * 16 + quad * 4;
    float bi[4];
#pragma unroll
    for (int r = 0; r < 4; ++r) bi[r] = bias[mrow + r];
#pragma unroll
    for (int ni = 0; ni < 2; ++ni) {
      const int ncol = n0 + wn + ni * 16 + fm;
      const long base = (long)ncol * Cout + mrow;
      ushort4 u;
      u.x = f2bf(fmaxf(acc[mi][ni][0] + bi[0], 0.f));
      u.y = f2bf(fmaxf(acc[mi][ni][1] + bi[1], 0.f));
      u.z = f2bf(fmaxf(acc[mi][ni][2] + bi[2], 0.f));
      u.w = f2bf(fmaxf(acc[mi][ni][3] + bi[3], 0.f));
      *(ushort4*)(Y + base) = u;
    }
  }
}

__global__ __launch_bounds__(256) void k_conv1(
    const bf16* __restrict__ keysT, const bf16* __restrict__ w1T,
    const float* __restrict__ b_k1, bf16* __restrict__ ke1T,
    const bf16* __restrict__ queriesT, const bf16* __restrict__ qw1T,
    const float* __restrict__ b_q1, bf16* __restrict__ qe1T) {
  __shared__ __align__(16) short sA[128 * LDSW2];
  __shared__ __align__(16) short sB[64 * LDSW2];
  int j = blockIdx.x;
  if (j < 200) {
    conv_tile128(keysT, w1T, b_k1, ke1T, (j / 25) * 128, (j % 25) * 64, sA, sB);
  } else {
    j -= 200;
    conv_tile(queriesT, qw1T, b_q1, qe1T, CM, 160, T1_, 3, 1, 1, 0,
              (j / 100) * 64, (j % 100) * 64, sA, sA + 64 * LDSW);
  }
}

// ---------------------------------------------------------------------------
// Fused query conv2+conv3 (R11-proven) + qn (||q||^2) epilogue.
// ---------------------------------------------------------------------------
__device__ void conv23_tile(
    const bf16* __restrict__ qe1T, const bf16* __restrict__ qw2c,
    const float* __restrict__ b_q2, const bf16* __restrict__ qw3c,
    const float* __restrict__ b_q3, float* __restrict__ qeT,
    float* __restrict__ qn, int n0, short* smem) {
  short* sIn = smem;
  short* sW2 = smem + 64 * LDSW3;
  short* sC  = smem;
  short* sW3 = smem + 64 * LDSW3;
  const int tid = threadIdx.x;
  const int wave = tid >> 6;
  const int lane = tid & 63;
  const int fm = lane & 15;
  const int quad = lane >> 4;

#pragma unroll
  for (int c = tid; c < 1280; c += 256) {
    const int row = c / 20, kc = (c - row * 20) * 8;
    uint4 v = *(const uint4*)(qe1T + (long)(n0 + row) * 160 + kc);
    *(uint4*)(sIn + row * LDSW3 + kc) = v;
  }
  for (int c = tid; c < 1600; c += 256) {
    const int row = c / 20, kc = (c - row * 20) * 8;
    uint4 v = *(const uint4*)(qw2c + (long)row * 160 + kc);
    *(uint4*)(sW2 + row * LDSW3 + kc) = v;
  }
  __syncthreads();

  f32x4 acc1[5] = {};
#pragma unroll
  for (int ks = 0; ks < 5; ++ks) {
    bf16x8 b = *(const bf16x8*)(sIn + (16 * wave + fm) * LDSW3 + ks * 32 + quad * 8);
#pragma unroll
    for (int mt = 0; mt < 5; ++mt) {
      bf16x8 a = *(const bf16x8*)(sW2 + (16 * mt + fm) * LDSW3 + ks * 32 + quad * 8);
      acc1[mt] = __builtin_amdgcn_mfma_f32_16x16x32_bf16(a, b, acc1[mt], 0, 0, 0);
    }
  }
  __syncthreads();

#pragma unroll
  for (int mt = 0; mt < 5; ++mt) {
    const int ch = 16 * mt + quad * 4;
    const float4 b2 = *(const float4*)(b_q2 + ch);
    ushort4 u;
    u.x = f2bf(fmaxf(acc1[mt][0] + b2.x, 0.f));
    u.y = f2bf(fmaxf(acc1[mt][1] + b2.y, 0.f));
    u.z = f2bf(fmaxf(acc1[mt][2] + b2.z, 0.f));
    u.w = f2bf(fmaxf(acc1[mt][3] + b2.w, 0.f));
    *(ushort4*)(sC + (16 * wave + fm) * LDSW4 + ch) = u;
  }
  if (tid < 128) {
    const int row = tid >> 1, off = 80 + (tid & 1) * 8;
    uint4 z = {0u, 0u, 0u, 0u};
    *(uint4*)(sC + row * LDSW4 + off) = z;
  }
  for (int c = tid; c < 800; c += 256) {
    const int row = c / 10, kc = (c - row * 10) * 8;
    uint4 v = *(const uint4*)(qw3c + (long)row * 80 + kc);
    *(uint4*)(sW3 + row * LDSW4 + kc) = v;
  }
  if (tid < 160) {
    const int row = tid >> 1, off = 80 + (tid & 1) * 8;
    uint4 z = {0u, 0u, 0u, 0u};
    *(uint4*)(sW3 + row * LDSW4 + off) = z;
  }
  __syncthreads();

  f32x4 acc2[5] = {};
#pragma unroll
  for (int ks = 0; ks < 3; ++ks) {
    bf16x8 b = *(const bf16x8*)(sC + (16 * wave + fm) * LDSW4 + ks * 32 + quad * 8);
#pragma unroll
    for (int mt = 0; mt < 5; ++mt) {
      bf16x8 a = *(const bf16x8*)(sW3 + (16 * mt + fm) * LDSW4 + ks * 32 + quad * 8);
      acc2[mt] = __builtin_amdgcn_mfma_f32_16x16x32_bf16(a, b, acc2[mt], 0, 0, 0);
    }
  }

  const int pos = n0 + 16 * wave + fm;
  float p = 0.f;   // partial ||q||^2 over this lane's 20 channels
#pragma unroll
  for (int mt = 0; mt < 5; ++mt) {
    const int ch = 16 * mt + quad * 4;
    const float4 b3 = *(const float4*)(b_q3 + ch);
    float4 o = make_float4(acc2[mt][0] + b3.x, acc2[mt][1] + b3.y,
                           acc2[mt][2] + b3.z, acc2[mt][3] + b3.w);
    p = fmaf(o.x, o.x, p); p = fmaf(o.y, o.y, p);
    p = fmaf(o.z, o.z, p); p = fmaf(o.w, o.w, p);
    *(float4*)(qeT + (long)pos * CA + ch) = o;
  }
  // cross-quad sum (lanes with same fm): quads 0..3
  p += __shfl_xor(p, 16, 64);
  p += __shfl_xor(p, 32, 64);
  if (quad == 0) qn[pos] = p;
}

__global__ __launch_bounds__(256) void k_conv2f(
    const bf16* __restrict__ ke1T, const bf16* __restrict__ kw2c,
    const float* __restrict__ b_k2, float* __restrict__ keT,
    float* __restrict__ kn,
    const bf16* __restrict__ qe1T, const bf16* __restrict__ qw2c,
    const float* __restrict__ b_q2, const bf16* __restrict__ qw3c,
    const float* __restrict__ b_q3, float* __restrict__ qeT,
    float* __restrict__ qn) {
  __shared__ __align__(16) short smem[64 * LDSW3 + 80 * LDSW3];
  int j = blockIdx.x;
  if (j < 50) {
    conv_tile(ke1T, kw2c, b_k2, keT, 1024, CA, T2_, 1, 0, 0, 2,
              (j / 25) * 64, (j % 25) * 64, smem, smem + 64 * LDSW, kn);
  } else {
    conv23_tile(qe1T, qw2c, b_q2, qw3c, b_q3, qeT, qn, (j - 50) * 64, smem);
  }
}

// ---------------------------------------------------------------------------
// dist: 4 t1-rows per block. keT holds -2k channel-major [b][80][200] ->
// lane t2 loads are coalesced; x = -5e-4*(sum(-2k*q) + ||q||^2 + ||k||^2).
// 4-phase ILP reduction (R11-proven machinery).
// ---------------------------------------------------------------------------
__global__ __launch_bounds__(256) void k_dist(
    const float* __restrict__ qeT, const float* __restrict__ keT2,
    const float* __restrict__ kn, const float* __restrict__ qn,
    const void* __restrict__ prior, const float* __restrict__ mf,
    void* __restrict__ out, const unsigned short* __restrict__ qprobe) {
  __shared__ float sq[4 * CA];
  __shared__ float sqn[4];
  __shared__ float redA[16], redB[16], redC[16], redD[16];
  const int f = detect_f32(qprobe);
  const int b = blockIdx.y;
  const int t1base = blockIdx.x * 4;
  const int tid = threadIdx.x;
  const int wid = tid >> 6;

  for (int i = tid; i < 4 * CA; i += 256) {
    int u = i / CA, c = i - u * CA;
    sq[i] = qeT[((long)b * T1_ + t1base + u) * CA + c];
  }
  if (tid < 4) sqn[tid] = qn[b * T1_ + t1base + tid];
  __syncthreads();

  const int t2 = tid;
  const bool valid = (t2 < T2_);
  float x[4] = {-INFINITY, -INFINITY, -INFINITY, -INFINITY};
  if (valid) {
    const float* kp = keT2 + (long)b * CA * T2_ + t2;
    const float knv = kn[b * T2_ + t2];
    float s[4] = {0.f, 0.f, 0.f, 0.f};
#pragma unroll 8
    for (int j = 0; j < CA; ++j) {
      const float kv = kp[j * T2_];   // coalesced across lanes
      s[0] = fmaf(kv, sq[0 * CA + j], s[0]);
      s[1] = fmaf(kv, sq[1 * CA + j], s[1]);
      s[2] = fmaf(kv, sq[2 * CA + j], s[2]);
      s[3] = fmaf(kv, sq[3 * CA + j], s[3]);
    }
#pragma unroll
    for (int u = 0; u < 4; ++u)
      x[u] = -0.0005f * (s[u] + sqn[u] + knv);
  }

  const float mval = valid ? mf[b * T2_ + t2] : 0.f;
  const long N = (long)B_ * T1_ * T2_;

  // --- phase 1: row maxima ---
  float m[4] = {x[0], x[1], x[2], x[3]};
#pragma unroll
  for (int o = 32; o > 0; o >>= 1)
#pragma unroll
    for (int u = 0; u < 4; ++u) m[u] = fmaxf(m[u], __shfl_down(m[u], o, 64));
  if ((tid & 63) == 0)
#pragma unroll
    for (int u = 0; u < 4; ++u) redA[wid * 4 + u] = m[u];
  __syncthreads();
  float M1[4];
#pragma unroll
  for (int u = 0; u < 4; ++u)
    M1[u] = fmaxf(fmaxf(redA[u], redA[4 + u]), fmaxf(redA[8 + u], redA[12 + u]));

  // --- phase 2: sum of exp ---
  float e[4], s1[4];
#pragma unroll
  for (int u = 0; u < 4; ++u) {
    e[u] = (x[u] == -INFINITY) ? 0.f : expf(x[u] - M1[u]);
    s1[u] = e[u];
  }
#pragma unroll
  for (int o = 32; o > 0; o >>= 1)
#pragma unroll
    for (int u = 0; u < 4; ++u) s1[u] += __shfl_down(s1[u], o, 64);
  if ((tid & 63) == 0)
#pragma unroll
    for (int u = 0; u < 4; ++u) redB[wid * 4 + u] = s1[u];
  __syncthreads();
  float lp[4];
#pragma unroll
  for (int u = 0; u < 4; ++u) {
    const float S1 = redB[u] + redB[4 + u] + redB[8 + u] + redB[12 + u];
    const float logZ = logf(S1);
    lp[u] = -INFINITY;
    if (valid) {
      const long oidx = ((long)b * T1_ + t1base + u) * T2_ + t2;
      float pr = load_sel(prior, oidx, f);
      lp[u] = (x[u] - M1[u] - logZ) + logf(fmaxf(pr, 0.f) + 1e-8f);
      if (f) ((float*)out)[N + oidx] = lp[u];
      else   ((bf16*)out)[N + oidx] = __float2bfloat16(lp[u]);
    }
  }

  // --- phase 3: masked maxima ---
  float xm[4], m2[4];
#pragma unroll
  for (int u = 0; u < 4; ++u) {
    xm[u] = (valid && mval != 0.f) ? -INFINITY : lp[u];
    m2[u] = xm[u];
  }
#pragma unroll
  for (int o = 32; o > 0; o >>= 1)
#pragma unroll
    for (int u = 0; u < 4; ++u) m2[u] = fmaxf(m2[u], __shfl_down(m2[u], o, 64));
  if ((tid & 63) == 0)
#pragma unroll
    for (int u = 0; u < 4; ++u) redC[wid * 4 + u] = m2[u];
  __syncthreads();
  float M2[4];
#pragma unroll
  for (int u = 0; u < 4; ++u)
    M2[u] = fmaxf(fmaxf(redC[u], redC[4 + u]), fmaxf(redC[8 + u], redC[12 + u]));

  // --- phase 4: masked sum + final write ---
  float e2[4], s2[4];
#pragma unroll
  for (int u = 0; u < 4; ++u) {
    e2[u] = (xm[u] == -INFINITY) ? 0.f : expf(xm[u] - M2[u]);
    s2[u] = e2[u];
  }
#pragma unroll
  for (int o = 32; o > 0; o >>= 1)
#pragma unroll
    for (int u = 0; u < 4; ++u) s2[u] += __shfl_down(s2[u], o, 64);
  if ((tid & 63) == 0)
#pragma unroll
    for (int u = 0; u < 4; ++u) redD[wid * 4 + u] = s2[u];
  __syncthreads();
#pragma unroll
  for (int u = 0; u < 4; ++u) {
    const float S2 = redD[u] + redD[4 + u] + redD[8 + u] + redD[12 + u];
    if (valid) {
      float a = (S2 > 0.f) ? (e2[u] / S2) : 0.f;
      const long oidx = ((long)b * T1_ + t1base + u) * T2_ + t2;
      if (f) ((float*)out)[oidx] = a;
      else   ((bf16*)out)[oidx] = __float2bfloat16(a);
    }
  }
}

// ---------------------------------------------------------------------------
extern "C" void kernel_launch(void* const* d_in, const int* in_sizes, int n_in,
                              void* d_out, int out_size, void* d_ws, size_t ws_size,
                              hipStream_t stream) {
  const void* queries = d_in[0];
  const void* keys    = d_in[1];
  const void* mask    = d_in[3];
  const void* prior   = d_in[4];
  const void* kp_w1 = d_in[5];
  const void* kp_b1 = d_in[6];
  const void* kp_w2 = d_in[7];
  const void* kp_b2 = d_in[8];
  const void* qp_w1 = d_in[9];
  const void* qp_b1 = d_in[10];
  const void* qp_w2 = d_in[11];
  const void* qp_b2 = d_in[12];
  const void* qp_w3 = d_in[13];
  const void* qp_b3 = d_in[14];

  // ---- Workspace ----
  float* keT   = (float*)d_ws;            // 128,000 f  [b][80][200] = -2k
  float* qeT   = keT + 128000;            // 512,000 f  [b][800][80]
  float* mf    = qeT + 512000;            //   1,600 f
  float* biasf = mf + 1600;               //   1,440 f
  float* kn    = biasf + 1440;            //   1,600 f  ||k||^2
  float* qn    = kn + 1600;               //   6,400 f  ||q||^2
  bf16* keysT    = (bf16*)(qn + 6400);    //   819,200
  bf16* queriesT = keysT + 819200;        //   512,000
  bf16* w1T      = queriesT + 512000;     // 1,572,864
  bf16* qw1T     = w1T + 1572864;         //    38,400
  bf16* kw2c     = qw1T + 38400;          //    81,920
  bf16* qw2c     = kw2c + 81920;          //    12,800
  bf16* qw3c     = qw2c + 12800;          //     6,400
  bf16* ke1T     = qw3c + 6400;           // 1,638,400
  bf16* qe1T     = ke1T + 1638400;        // 1,024,000

  float* b_k1 = biasf;          // 1024
  float* b_k2 = biasf + 1024;   // 80
  float* b_q1 = biasf + 1104;   // 160
  float* b_q2 = biasf + 1264;   // 80
  float* b_q3 = biasf + 1344;   // 80

  // 1) fused prep (also zeroes kn)
  k_prep<<<2123, 256, 0, stream>>>(
      queries, keys, mask,
      kp_w1, kp_b1, kp_w2, kp_b2,
      qp_w1, qp_b1, qp_w2, qp_b2, qp_w3, qp_b3,
      keysT, queriesT, w1T, qw1T, kw2c, qw2c, qw3c, biasf, mf, kn);

  // 2) conv1: key 128x64 (200) + query 64x64 (300)
  k_conv1<<<500, 256, 0, stream>>>(keysT, w1T, b_k1, ke1T,
                                   queriesT, qw1T, b_q1, qe1T);

  // 3) key conv2 -> -2k + kn (50) + fused query conv2+3 -> qeT + qn (100)
  k_conv2f<<<150, 256, 0, stream>>>(ke1T, kw2c, b_k2, keT, kn,
                                    qe1T, qw2c, b_q2, qw3c, b_q3, qeT, qn);

  // 4) dist
  k_dist<<<dim3(200, B_), 256, 0, stream>>>(
      qeT, keT, kn, qn, prior, mf, d_out, (const unsigned short*)queries);
}